// Round 9
// baseline (669.770 us; speedup 1.0000x reference)
//
#include <hip/hip_runtime.h>

typedef __attribute__((ext_vector_type(8))) short bf16x8;
typedef __attribute__((ext_vector_type(4))) float f32x4;
typedef __attribute__((ext_vector_type(2))) float f32x2;

static __device__ __forceinline__ unsigned short f2bf(float f) {
    unsigned int u = __float_as_uint(f);
    u += 0x7fffu + ((u >> 16) & 1u);   // round-to-nearest-even
    return (unsigned short)(u >> 16);
}
static __device__ __forceinline__ float bf2f(unsigned short h) {
    return __uint_as_float(((unsigned int)h) << 16);
}

#define BSH 6
#define BUCKET 64
#define NBMAX 1600
#define CHSH 13

// ---------------- structs ----------------

struct Rel {
    const int* src; const int* dst; int E; int nb; int Ndst;
    int hblk0, hnblk;
    int sblk0, snblk;
    int oblk0;
    int shift;                 // ssrc stores (s << shift) byte offsets
    int* bcnt; int* boff; int* bcur;
    unsigned* pairs; unsigned* ssrc; int* goff; float* invd;
};
struct Rels { Rel r[3]; };

struct PrepArgs {
    const float* W[10];
    const float* Wa[10];
    const float* b1a; const float* b1b; const float* b2a; const float* b2b;
};

// ---------------- prep + bucket-hist (merged) ----------------

__global__ void prep_hist_k(PrepArgs pa, unsigned short* __restrict__ Wt,
                            float* __restrict__ bc1, float* __restrict__ bc2,
                            Rels R, int prepBlocks) {
    int bid = blockIdx.x;
    if (bid < prepBlocks) {
        if (bid < 640) {
            int slot = bid >> 6;
            int i = ((bid & 63) << 8) + threadIdx.x;
            float v = pa.W[slot][i];
            const float* w2 = pa.Wa[slot];
            if (w2) v += w2[i];
            int k = i >> 7, n = i & 127;
            Wt[slot * 16384 + n * 128 + k] = f2bf(v);
        } else {
            int t = threadIdx.x;
            if (t < 128) bc1[t] = pa.b1a[t] + pa.b1b[t];
            else bc2[t - 128] = pa.b2a[t - 128] + pa.b2b[t - 128];
        }
        return;
    }
    int hb = bid - prepBlocks;
    const Rel* r;
    if (hb < R.r[1].hblk0) r = &R.r[0];
    else if (hb < R.r[2].hblk0) r = &R.r[1];
    else r = &R.r[2];
    __shared__ int h[NBMAX];
    for (int i = threadIdx.x; i < r->nb; i += 256) h[i] = 0;
    __syncthreads();
    for (int e = (hb - r->hblk0) * 256 + threadIdx.x; e < r->E; e += r->hnblk * 256)
        atomicAdd(&h[r->dst[e] >> BSH], 1);
    __syncthreads();
    for (int i = threadIdx.x; i < r->nb; i += 256)
        if (h[i]) atomicAdd(&r->bcnt[i], h[i]);
}

// ---------------- scan + scatter ----------------

__global__ void bscan3_k(Rels R) {
    const Rel* r = &R.r[blockIdx.x];
    __shared__ int s[1024];
    int t = threadIdx.x;
    int nb = r->nb;
    int e0 = 2 * t, e1 = 2 * t + 1;
    int v0 = (e0 < nb) ? r->bcnt[e0] : 0;
    int v1 = (e1 < nb) ? r->bcnt[e1] : 0;
    s[t] = v0 + v1;
    __syncthreads();
    for (int o = 1; o < 1024; o <<= 1) {
        int x = (t >= o) ? s[t - o] : 0;
        __syncthreads();
        s[t] += x;
        __syncthreads();
    }
    int P = s[t] - (v0 + v1);
    if (e0 <= nb) { r->boff[e0] = P; if (e0 < nb) r->bcur[e0] = 0; }
    if (e1 <= nb) { r->boff[e1] = P + v0; if (e1 < nb) r->bcur[e1] = 0; }
}

__global__ __launch_bounds__(256) void bscatter3_k(Rels R) {
    const Rel* r;
    int bid = blockIdx.x;
    if (bid < R.r[1].sblk0) r = &R.r[0];
    else if (bid < R.r[2].sblk0) r = &R.r[1];
    else r = &R.r[2];
    __shared__ int h[NBMAX];
    __shared__ int base[NBMAX];
    int t = threadIdx.x;
    int nb = r->nb, E = r->E;
    for (int i = t; i < nb; i += 256) h[i] = 0;
    __syncthreads();
    int e0 = (bid - r->sblk0) * 8192;
    for (int i = 0; i < 32; i++) {
        int e = e0 + i * 256 + t;
        if (e < E) atomicAdd(&h[r->dst[e] >> BSH], 1);
    }
    __syncthreads();
    for (int i = t; i < nb; i += 256) {
        int c = h[i];
        base[i] = c ? (r->boff[i] + atomicAdd(&r->bcur[i], c)) : 0;
    }
    __syncthreads();
    for (int i = t; i < nb; i += 256) h[i] = 0;
    __syncthreads();
    for (int i = 0; i < 32; i++) {
        int e = e0 + i * 256 + t;
        if (e < E) {
            int d = r->dst[e];
            int b = d >> BSH;
            int pos = base[b] + atomicAdd(&h[b], 1);
            r->pairs[pos] = ((unsigned)(d & (BUCKET - 1)) << 17) | (unsigned)r->src[e];
        }
    }
}

// ---------------- per-bucket counting sort (device body) ----------------
// bin = ((d&7)<<7) | ((d>>3)<<4) | ch; run (16 bins) = (wave w=d&7, row r=d>>3).
static __device__ void sortb_body(const Rels& R, int bid) {
    const Rel* r;
    if (bid < R.r[1].oblk0) r = &R.r[0];
    else if (bid < R.r[2].oblk0) r = &R.r[1];
    else r = &R.r[2];
    int b = bid - r->oblk0;
    __shared__ int cnt[1024];
    __shared__ int sc[256];
    int t = threadIdx.x;
    for (int i = t; i < 1024; i += 256) cnt[i] = 0;
    __syncthreads();
    int j0 = r->boff[b], j1 = r->boff[b + 1];
    for (int j = j0 + t; j < j1; j += 256) {
        unsigned p = r->pairs[j];
        int d = (p >> 17) & 63;
        int ch = (int)((p & 0x1ffffu) >> CHSH); if (ch > 15) ch = 15;
        int bin = ((d & 7) << 7) | ((d >> 3) << 4) | ch;
        atomicAdd(&cnt[bin], 1);
    }
    __syncthreads();
    if (t < 64) {
        int b0 = ((t & 7) << 7) | ((t >> 3) << 4);
        int c = 0;
#pragma unroll
        for (int i = 0; i < 16; i++) c += cnt[b0 + i];
        int dd = (b << BSH) + t;
        if (dd < r->Ndst) r->invd[dd] = 1.f / (float)(c > 0 ? c : 1);
    }
    int c0 = cnt[4 * t], c1 = cnt[4 * t + 1], c2 = cnt[4 * t + 2], c3 = cnt[4 * t + 3];
    int tot = c0 + c1 + c2 + c3;
    sc[t] = tot;
    __syncthreads();
    for (int o = 1; o < 256; o <<= 1) {
        int x = (t >= o) ? sc[t - o] : 0;
        __syncthreads();
        sc[t] += x;
        __syncthreads();
    }
    int base = j0 + sc[t] - tot;
    if ((t & 3) == 0) r->goff[b * 64 + (t >> 2)] = base;
    cnt[4 * t] = base;
    cnt[4 * t + 1] = base + c0;
    cnt[4 * t + 2] = base + c0 + c1;
    cnt[4 * t + 3] = base + c0 + c1 + c2;
    if (t == 0 && b == r->nb - 1) r->goff[r->nb * 64] = r->E;
    __syncthreads();
    int shift = r->shift;
    for (int j = j0 + t; j < j1; j += 256) {
        unsigned p = r->pairs[j];
        int d = (p >> 17) & 63;
        int ch = (int)((p & 0x1ffffu) >> CHSH); if (ch > 15) ch = 15;
        int bin = ((d & 7) << 7) | ((d >> 3) << 4) | ch;
        int pos = atomicAdd(&cnt[bin], 1);
        r->ssrc[pos] = (p & 0x1ffffu) << shift;
    }
}

// ---------------- MFMA GEMM body ----------------

struct GemmJobs {
    const void* Akw; int Nkw;
    const unsigned short* Wk1; const float* bk; unsigned short* Zkw;
    const unsigned short* Wk2; unsigned char* Ckw8;
    const void* Art; int Nrt;
    const unsigned short* Wr1; const float* br; unsigned short* Zrt;
    const unsigned short* Wr2; unsigned short* Crt2;
    const unsigned short* Wr3; unsigned short* Crt3;
    int kwBlocks;
};

template <int AF32>
static __device__ void gemm_body(const GemmJobs& G, int bid) {
    bool iskw = bid < G.kwBlocks;
    const void* A = iskw ? G.Akw : G.Art;
    int N = iskw ? G.Nkw : G.Nrt;
    int lane = threadIdx.x & 63;
    int r16 = lane & 15, g = lane >> 4;
    int row0 = (iskw ? bid : bid - G.kwBlocks) * 64 + (threadIdx.x >> 6) * 16;
    int arow = row0 + r16;
    int arow_c = arow < N ? arow : N - 1;

    bf16x8 af[4];
    if (AF32) {
        const float* Af = (const float*)A + (size_t)arow_c * 128 + g * 8;
#pragma unroll
        for (int kc = 0; kc < 4; kc++) {
            float4 u0 = *(const float4*)(Af + kc * 32);
            float4 u1 = *(const float4*)(Af + kc * 32 + 4);
            bf16x8 rr;
            rr[0] = (short)f2bf(u0.x); rr[1] = (short)f2bf(u0.y);
            rr[2] = (short)f2bf(u0.z); rr[3] = (short)f2bf(u0.w);
            rr[4] = (short)f2bf(u1.x); rr[5] = (short)f2bf(u1.y);
            rr[6] = (short)f2bf(u1.z); rr[7] = (short)f2bf(u1.w);
            af[kc] = rr;
        }
    } else {
        const bf16x8* Ar = (const bf16x8*)((const unsigned short*)A + (size_t)arow_c * 128);
#pragma unroll
        for (int kc = 0; kc < 4; kc++) af[kc] = Ar[kc * 4 + g];
    }

    if (iskw) {
        f32x4 acc1[8], acc2[8];
#pragma unroll
        for (int ct = 0; ct < 8; ct++) { f32x4 z = {0.f,0.f,0.f,0.f}; acc1[ct] = z; acc2[ct] = z; }
#pragma unroll
        for (int kc = 0; kc < 4; kc++) {
#pragma unroll
            for (int ct = 0; ct < 8; ct++) {
                int wo = ((ct * 16 + r16) << 7) + kc * 32 + g * 8;
                bf16x8 b1 = *(const bf16x8*)(G.Wk1 + wo);
                acc1[ct] = __builtin_amdgcn_mfma_f32_16x16x32_bf16(af[kc], b1, acc1[ct], 0, 0, 0);
                bf16x8 b2 = *(const bf16x8*)(G.Wk2 + wo);
                acc2[ct] = __builtin_amdgcn_mfma_f32_16x16x32_bf16(af[kc], b2, acc2[ct], 0, 0, 0);
            }
        }
#pragma unroll
        for (int ct = 0; ct < 8; ct++) {
            int col = ct * 16 + r16;
            float bb = G.bk[col];
#pragma unroll
            for (int j = 0; j < 4; j++) {
                int r = row0 + g * 4 + j;
                if (r < N) {
                    G.Zkw[(size_t)r * 128 + col] = f2bf(acc1[ct][j] + bb);
                    float v2 = acc2[ct][j];
                    int pk = __builtin_amdgcn_cvt_pk_fp8_f32(v2, v2, 0, false);
                    G.Ckw8[(size_t)r * 128 + col] = (unsigned char)(pk & 0xff);
                }
            }
        }
    } else {
        f32x4 acc1[8], acc2[8], acc3[8];
#pragma unroll
        for (int ct = 0; ct < 8; ct++) {
            f32x4 z = {0.f,0.f,0.f,0.f}; acc1[ct] = z; acc2[ct] = z; acc3[ct] = z;
        }
#pragma unroll
        for (int kc = 0; kc < 4; kc++) {
#pragma unroll
            for (int ct = 0; ct < 8; ct++) {
                int wo = ((ct * 16 + r16) << 7) + kc * 32 + g * 8;
                bf16x8 b1 = *(const bf16x8*)(G.Wr1 + wo);
                acc1[ct] = __builtin_amdgcn_mfma_f32_16x16x32_bf16(af[kc], b1, acc1[ct], 0, 0, 0);
                bf16x8 b2 = *(const bf16x8*)(G.Wr2 + wo);
                acc2[ct] = __builtin_amdgcn_mfma_f32_16x16x32_bf16(af[kc], b2, acc2[ct], 0, 0, 0);
                bf16x8 b3 = *(const bf16x8*)(G.Wr3 + wo);
                acc3[ct] = __builtin_amdgcn_mfma_f32_16x16x32_bf16(af[kc], b3, acc3[ct], 0, 0, 0);
            }
        }
#pragma unroll
        for (int ct = 0; ct < 8; ct++) {
            int col = ct * 16 + r16;
            float bb = G.br[col];
#pragma unroll
            for (int j = 0; j < 4; j++) {
                int r = row0 + g * 4 + j;
                if (r < N) {
                    G.Zrt[(size_t)r * 128 + col] = f2bf(acc1[ct][j] + bb);
                    G.Crt2[(size_t)r * 128 + col] = f2bf(acc2[ct][j]);
                    G.Crt3[(size_t)r * 128 + col] = f2bf(acc3[ct][j]);
                }
            }
        }
    }
}

__global__ __launch_bounds__(256) void gemm_sort_k(GemmJobs G, Rels R, int gemmBlocks) {
    if ((int)blockIdx.x < gemmBlocks) gemm_body<1>(G, blockIdx.x);
    else sortb_body(R, blockIdx.x - gemmBlocks);
}

__global__ __launch_bounds__(256) void gemm_l2_k(GemmJobs G) {
    gemm_body<0>(G, blockIdx.x);
}

// ---------------- bucket aggregation ----------------
// Block = one 64-dst bucket, 8 waves. Wave w owns rows d=(r<<3)|w. Quarter-wave
// group g=lane>>4 takes edge 4k+g of each batch; lane covers features 8q..8q+7
// (q=lane&15) via one uint4 (bf16) / uint2 (fp8) load -> 4 edges per VMEM inst.
// ssrc byte-offsets broadcast: 1 wave load per 32 edges + ds_bpermute (DS pipe).
// Reduce across groups via shfl_xor(16/32); exclusive swizzled LDS flush.
template <int FMT>   // 0: bf16 rows (256B), 1: fp8 rows (128B)
static __device__ __forceinline__ void agg_rel(float* acc, int b, int w, int lane,
                                               int dst0,
                                               const unsigned* __restrict__ sp,
                                               const int* __restrict__ goff,
                                               const float* __restrict__ invd,
                                               const char* __restrict__ Ybase) {
    int g = lane >> 4, q = lane & 15;
    int lb = FMT ? (q << 3) : (q << 4);
    int idx0 = (0 + g) << 2, idx1 = (4 + g) << 2, idx2 = (8 + g) << 2, idx3 = (12 + g) << 2;
    int loc0 = (((2 * g) & 3) << 5) + 2 * q + (g >> 1);
    int loc1 = (((2 * g + 1) & 3) << 5) + 2 * q + (g >> 1);
#pragma unroll 1
    for (int r = 0; r < 8; r++) {
        int gi = b * 64 + w * 8 + r;
        int jg0 = goff[gi], jg1 = goff[gi + 1];
        if (jg0 >= jg1) continue;
        int d = (r << 3) | w;
        f32x2 a01 = {0.f, 0.f}, a23 = {0.f, 0.f}, a45 = {0.f, 0.f}, a67 = {0.f, 0.f};
#pragma unroll 1
        for (int jb = jg0; jb < jg1; jb += 32) {
            int ji = jb + (lane & 31);
            ji = ji < jg1 ? ji : jg1 - 1;
            int spv = (int)sp[ji];                       // 1 VMEM per 32 edges
            if (jb + 32 <= jg1) {                        // full super-batch
#pragma unroll
                for (int hb = 0; hb < 2; hb++) {
                    int hofs = hb << 6;
                    unsigned o0 = (unsigned)__builtin_amdgcn_ds_bpermute(idx0 + hofs, spv);
                    unsigned o1 = (unsigned)__builtin_amdgcn_ds_bpermute(idx1 + hofs, spv);
                    unsigned o2 = (unsigned)__builtin_amdgcn_ds_bpermute(idx2 + hofs, spv);
                    unsigned o3 = (unsigned)__builtin_amdgcn_ds_bpermute(idx3 + hofs, spv);
                    if (FMT == 0) {
                        uint4 v0 = *(const uint4*)(Ybase + o0 + lb);
                        uint4 v1 = *(const uint4*)(Ybase + o1 + lb);
                        uint4 v2 = *(const uint4*)(Ybase + o2 + lb);
                        uint4 v3 = *(const uint4*)(Ybase + o3 + lb);
#pragma unroll
                        for (int k = 0; k < 4; k++) {
                            uint4 v = k == 0 ? v0 : k == 1 ? v1 : k == 2 ? v2 : v3;
                            f32x2 x0 = { __uint_as_float(v.x << 16), __uint_as_float(v.x & 0xffff0000u) };
                            f32x2 x1 = { __uint_as_float(v.y << 16), __uint_as_float(v.y & 0xffff0000u) };
                            f32x2 x2 = { __uint_as_float(v.z << 16), __uint_as_float(v.z & 0xffff0000u) };
                            f32x2 x3 = { __uint_as_float(v.w << 16), __uint_as_float(v.w & 0xffff0000u) };
                            a01 += x0; a23 += x1; a45 += x2; a67 += x3;
                        }
                    } else {
                        uint2 v0 = *(const uint2*)(Ybase + o0 + lb);
                        uint2 v1 = *(const uint2*)(Ybase + o1 + lb);
                        uint2 v2 = *(const uint2*)(Ybase + o2 + lb);
                        uint2 v3 = *(const uint2*)(Ybase + o3 + lb);
#pragma unroll
                        for (int k = 0; k < 4; k++) {
                            uint2 v = k == 0 ? v0 : k == 1 ? v1 : k == 2 ? v2 : v3;
                            auto l0 = __builtin_amdgcn_cvt_pk_f32_fp8(v.x, false);
                            auto h0 = __builtin_amdgcn_cvt_pk_f32_fp8(v.x, true);
                            auto l1 = __builtin_amdgcn_cvt_pk_f32_fp8(v.y, false);
                            auto h1 = __builtin_amdgcn_cvt_pk_f32_fp8(v.y, true);
                            a01[0] += l0[0]; a01[1] += l0[1];
                            a23[0] += h0[0]; a23[1] += h0[1];
                            a45[0] += l1[0]; a45[1] += l1[1];
                            a67[0] += h1[0]; a67[1] += h1[1];
                        }
                    }
                }
            } else {                                     // tail: predicated
#pragma unroll
                for (int hb = 0; hb < 2; hb++) {
                    int ebase = jb + (hb << 4) + g;
                    if (ebase >= jg1 && g == 0) {}       // uniform-ish skip below
                    if (jb + (hb << 4) >= jg1) break;
                    int hofs = hb << 6;
                    unsigned o0 = (unsigned)__builtin_amdgcn_ds_bpermute(idx0 + hofs, spv);
                    unsigned o1 = (unsigned)__builtin_amdgcn_ds_bpermute(idx1 + hofs, spv);
                    unsigned o2 = (unsigned)__builtin_amdgcn_ds_bpermute(idx2 + hofs, spv);
                    unsigned o3 = (unsigned)__builtin_amdgcn_ds_bpermute(idx3 + hofs, spv);
#pragma unroll
                    for (int k = 0; k < 4; k++) {
                        unsigned ok = k == 0 ? o0 : k == 1 ? o1 : k == 2 ? o2 : o3;
                        bool live = (jb + (hb << 4) + 4 * k + g) < jg1;
                        if (FMT == 0) {
                            uint4 v = *(const uint4*)(Ybase + ok + lb);
                            unsigned vx = live ? v.x : 0u, vy = live ? v.y : 0u;
                            unsigned vz = live ? v.z : 0u, vw = live ? v.w : 0u;
                            f32x2 x0 = { __uint_as_float(vx << 16), __uint_as_float(vx & 0xffff0000u) };
                            f32x2 x1 = { __uint_as_float(vy << 16), __uint_as_float(vy & 0xffff0000u) };
                            f32x2 x2 = { __uint_as_float(vz << 16), __uint_as_float(vz & 0xffff0000u) };
                            f32x2 x3 = { __uint_as_float(vw << 16), __uint_as_float(vw & 0xffff0000u) };
                            a01 += x0; a23 += x1; a45 += x2; a67 += x3;
                        } else {
                            uint2 v = *(const uint2*)(Ybase + ok + lb);
                            unsigned vx = live ? v.x : 0u, vy = live ? v.y : 0u;
                            auto l0 = __builtin_amdgcn_cvt_pk_f32_fp8(vx, false);
                            auto h0 = __builtin_amdgcn_cvt_pk_f32_fp8(vx, true);
                            auto l1 = __builtin_amdgcn_cvt_pk_f32_fp8(vy, false);
                            auto h1 = __builtin_amdgcn_cvt_pk_f32_fp8(vy, true);
                            a01[0] += l0[0]; a01[1] += l0[1];
                            a23[0] += h0[0]; a23[1] += h0[1];
                            a45[0] += l1[0]; a45[1] += l1[1];
                            a67[0] += h1[0]; a67[1] += h1[1];
                        }
                    }
                }
            }
        }
        // reduce across the 4 groups (each had different edges, same features)
        float s0 = a01[0], s1 = a01[1], s2 = a23[0], s3 = a23[1];
        float s4 = a45[0], s5 = a45[1], s6 = a67[0], s7 = a67[1];
        s0 += __shfl_xor(s0, 16); s0 += __shfl_xor(s0, 32);
        s1 += __shfl_xor(s1, 16); s1 += __shfl_xor(s1, 32);
        s2 += __shfl_xor(s2, 16); s2 += __shfl_xor(s2, 32);
        s3 += __shfl_xor(s3, 16); s3 += __shfl_xor(s3, 32);
        s4 += __shfl_xor(s4, 16); s4 += __shfl_xor(s4, 32);
        s5 += __shfl_xor(s5, 16); s5 += __shfl_xor(s5, 32);
        s6 += __shfl_xor(s6, 16); s6 += __shfl_xor(s6, 32);
        s7 += __shfl_xor(s7, 16); s7 += __shfl_xor(s7, 32);
        // group g flushes features 8q+2g, 8q+2g+1 (static select; stride-2 banks)
        float w0 = g == 0 ? s0 : g == 1 ? s2 : g == 2 ? s4 : s6;
        float w1 = g == 0 ? s1 : g == 1 ? s3 : g == 2 ? s5 : s7;
        float inv = invd[dst0 + d];
        int ba = d * 128;
        acc[ba + loc0] += w0 * inv;
        acc[ba + loc1] += w1 * inv;
    }
}

struct AggJob {
    const unsigned short* Zin; int Ndst;
    const unsigned* sp0; const int* goff0; const float* invd0; const void* Y0; int fmt0;
    const unsigned* sp1; const int* goff1; const float* invd1; const void* Y1; int fmt1;
    int nrel;
    float* OutF; unsigned short* OutB;
};

template <int RELU, int OUTBF16>
__global__ __launch_bounds__(512) void bagg2_k(AggJob JK, AggJob JR, int kwBlocks) {
    __shared__ float acc[BUCKET * 128];
    bool iskw = blockIdx.x < (unsigned)kwBlocks;
    AggJob J = iskw ? JK : JR;
    int b = iskw ? blockIdx.x : blockIdx.x - kwBlocks;
    int t = threadIdx.x;
    int dst0 = b << BSH;
    int nrow = J.Ndst - dst0; if (nrow > BUCKET) nrow = BUCKET;

    // init from Zin bf16 (swizzled: feature 4m+e at r*128 + e*32 + m)
    for (int c = t; c < BUCKET * 32; c += 512) {
        int r = c >> 5, m = c & 31;
        float z0 = 0.f, z1 = 0.f, z2 = 0.f, z3 = 0.f;
        if (r < nrow) {
            ushort4 z = *(const ushort4*)(J.Zin + (size_t)(dst0 + r) * 128 + (m << 2));
            z0 = bf2f(z.x); z1 = bf2f(z.y); z2 = bf2f(z.z); z3 = bf2f(z.w);
        }
        acc[r * 128 + m] = z0;
        acc[r * 128 + 32 + m] = z1;
        acc[r * 128 + 64 + m] = z2;
        acc[r * 128 + 96 + m] = z3;
    }
    __syncthreads();

    int w = t >> 6, lane = t & 63;
    if (J.fmt0 == 0) agg_rel<0>(acc, b, w, lane, dst0, J.sp0, J.goff0, J.invd0, (const char*)J.Y0);
    else agg_rel<1>(acc, b, w, lane, dst0, J.sp0, J.goff0, J.invd0, (const char*)J.Y0);
    if (J.nrel == 2) {
        if (J.fmt1 == 0) agg_rel<0>(acc, b, w, lane, dst0, J.sp1, J.goff1, J.invd1, (const char*)J.Y1);
        else agg_rel<1>(acc, b, w, lane, dst0, J.sp1, J.goff1, J.invd1, (const char*)J.Y1);
    }
    __syncthreads();
    for (int c = t; c < BUCKET * 32; c += 512) {
        int r = c >> 5, m = c & 31;
        if (r < nrow) {
            float x0 = acc[r * 128 + m];
            float x1 = acc[r * 128 + 32 + m];
            float x2 = acc[r * 128 + 64 + m];
            float x3 = acc[r * 128 + 96 + m];
            if (RELU) {
                x0 = fmaxf(x0, 0.f); x1 = fmaxf(x1, 0.f);
                x2 = fmaxf(x2, 0.f); x3 = fmaxf(x3, 0.f);
            }
            size_t o = (size_t)(dst0 + r) * 128 + (m << 2);
            if (OUTBF16) {
                ushort4 ov;
                ov.x = f2bf(x0); ov.y = f2bf(x1); ov.z = f2bf(x2); ov.w = f2bf(x3);
                *(ushort4*)(J.OutB + o) = ov;
            } else {
                *(float4*)(J.OutF + o) = make_float4(x0, x1, x2, x3);
            }
        }
    }
}

// ---------------- launch ----------------

static inline size_t align256(size_t x) { return (x + 255) & ~size_t(255); }

extern "C" void kernel_launch(void* const* d_in, const int* in_sizes, int n_in,
                              void* d_out, int out_size, void* d_ws, size_t ws_size,
                              hipStream_t stream) {
    const float* x_kw = (const float*)d_in[0];
    const float* x_rt = (const float*)d_in[1];
    const int* src_a = (const int*)d_in[2];
    const int* dst_a = (const int*)d_in[3];
    const int* src_b = (const int*)d_in[4];
    const int* dst_b = (const int*)d_in[5];
    const int* src_c = (const int*)d_in[6];
    const int* dst_c = (const int*)d_in[7];
    const float *Wl1a = (const float*)d_in[8],  *bl1a = (const float*)d_in[9],  *Wr1a = (const float*)d_in[10];
    const float *Wl1b = (const float*)d_in[11], *bl1b = (const float*)d_in[12], *Wr1b = (const float*)d_in[13];
    const float *Wl1c = (const float*)d_in[14], *bl1c = (const float*)d_in[15], *Wr1c = (const float*)d_in[16];
    const float *Wl2a = (const float*)d_in[17], *bl2a = (const float*)d_in[18], *Wr2a = (const float*)d_in[19];
    const float *Wl2b = (const float*)d_in[20], *bl2b = (const float*)d_in[21], *Wr2b = (const float*)d_in[22];
    const float *Wl2c = (const float*)d_in[23], *bl2c = (const float*)d_in[24], *Wr2c = (const float*)d_in[25];

    const int NKW = in_sizes[0] / 128;
    const int NRT = in_sizes[1] / 128;
    const int EA = in_sizes[2], EB = in_sizes[4], EC = in_sizes[6];
    const int nb_kw = (NKW + BUCKET - 1) / BUCKET;
    const int nb_rt = (NRT + BUCKET - 1) / BUCKET;

    char* ws = (char*)d_ws;
    size_t off = 0;
    auto alloc = [&](size_t bytes) -> char* {
        off = align256(off);
        char* p = ws + off;
        off += bytes;
        return p;
    };
    unsigned short* Wt = (unsigned short*)alloc(10 * 16384 * 2);
    float* bc1 = (float*)alloc(128 * 4);
    float* bc2 = (float*)alloc(128 * 4);
    int* bcnt3 = (int*)alloc(3 * NBMAX * 4);
    int* bcur3 = (int*)alloc(3 * NBMAX * 4);
    int* boff_a = (int*)alloc((NBMAX + 1) * 4);
    int* boff_b = (int*)alloc((NBMAX + 1) * 4);
    int* boff_c = (int*)alloc((NBMAX + 1) * 4);
    int* goff_a = (int*)alloc(((size_t)nb_kw * 64 + 1) * 4);
    int* goff_b = (int*)alloc(((size_t)nb_kw * 64 + 1) * 4);
    int* goff_c = (int*)alloc(((size_t)nb_rt * 64 + 1) * 4);
    float* invd_a = (float*)alloc((size_t)NKW * 4);
    float* invd_b = (float*)alloc((size_t)NKW * 4);
    float* invd_c = (float*)alloc((size_t)NRT * 4);
    unsigned* pairs_a = (unsigned*)alloc((size_t)EA * 4);
    unsigned* pairs_b = (unsigned*)alloc((size_t)EB * 4);
    unsigned* pairs_c = (unsigned*)alloc((size_t)EC * 4);
    unsigned* sp_a = (unsigned*)alloc((size_t)EA * 4);
    unsigned* sp_b = (unsigned*)alloc((size_t)EB * 4);
    unsigned* sp_c = (unsigned*)alloc((size_t)EC * 4);
    unsigned short* Ya = (unsigned short*)alloc((size_t)NRT * 128 * 2);
    unsigned char*  Yb = (unsigned char*)alloc((size_t)NKW * 128);      // fp8
    unsigned short* Yc = (unsigned short*)alloc((size_t)NRT * 128 * 2);
    unsigned short* Zkw = (unsigned short*)alloc((size_t)NKW * 128 * 2);
    unsigned short* Zrt = (unsigned short*)alloc((size_t)NRT * 128 * 2);
    unsigned short* kw1_bf = (unsigned short*)alloc((size_t)NKW * 128 * 2);
    unsigned short* rt1_bf = (unsigned short*)alloc((size_t)NRT * 128 * 2);
    (void)ws_size;

    float* out_kw = (float*)d_out;
    float* out_rt = out_kw + (size_t)NKW * 128;

    // ---- Rels ----
    Rels R;
    int hA = 128, hB = 128, hC = 64;
    int sA = (EA + 8191) / 8192, sB = (EB + 8191) / 8192, sC = (EC + 8191) / 8192;
    R.r[0] = {src_a, dst_a, EA, nb_kw, NKW, 0, hA, 0, sA, 0, 8,
              bcnt3, boff_a, bcur3, pairs_a, sp_a, goff_a, invd_a};
    R.r[1] = {src_b, dst_b, EB, nb_kw, NKW, hA, hB, sA, sB, nb_kw, 7,   // fp8 rows: 128 B
              bcnt3 + NBMAX, boff_b, bcur3 + NBMAX, pairs_b, sp_b, goff_b, invd_b};
    R.r[2] = {src_c, dst_c, EC, nb_rt, NRT, hA + hB, hC, sA + sB, sC, 2 * nb_kw, 8,
              bcnt3 + 2 * NBMAX, boff_c, bcur3 + 2 * NBMAX, pairs_c, sp_c, goff_c, invd_c};

    // ---- prep + hist ----
    hipMemsetAsync(bcnt3, 0, 3 * NBMAX * 4, stream);
    PrepArgs pa;
    pa.W[0] = Wr1a; pa.Wa[0] = Wr1b;
    pa.W[1] = Wl1a; pa.Wa[1] = nullptr;
    pa.W[2] = Wl1b; pa.Wa[2] = nullptr;
    pa.W[3] = Wl1c; pa.Wa[3] = nullptr;
    pa.W[4] = Wr1c; pa.Wa[4] = nullptr;
    pa.W[5] = Wr2a; pa.Wa[5] = Wr2b;
    pa.W[6] = Wl2a; pa.Wa[6] = nullptr;
    pa.W[7] = Wl2b; pa.Wa[7] = nullptr;
    pa.W[8] = Wl2c; pa.Wa[8] = nullptr;
    pa.W[9] = Wr2c; pa.Wa[9] = nullptr;
    pa.b1a = bl1a; pa.b1b = bl1b; pa.b2a = bl2a; pa.b2b = bl2b;
    prep_hist_k<<<641 + hA + hB + hC, 256, 0, stream>>>(pa, Wt, bc1, bc2, R, 641);
    unsigned short* W0 = Wt + 0 * 16384;
    unsigned short* W1 = Wt + 1 * 16384;
    unsigned short* W2 = Wt + 2 * 16384;
    unsigned short* W3 = Wt + 3 * 16384;
    unsigned short* W4 = Wt + 4 * 16384;
    unsigned short* W5 = Wt + 5 * 16384;
    unsigned short* W6 = Wt + 6 * 16384;
    unsigned short* W7 = Wt + 7 * 16384;
    unsigned short* W8 = Wt + 8 * 16384;
    unsigned short* W9 = Wt + 9 * 16384;

    bscan3_k<<<3, 1024, 0, stream>>>(R);
    bscatter3_k<<<sA + sB + sC, 256, 0, stream>>>(R);

    const int kwB = (NKW + 63) / 64, rtB = (NRT + 63) / 64;
    const int nsort = 2 * nb_kw + nb_rt;

    // ---- layer 1: gemms + bucket sort in one launch (independent) ----
    GemmJobs G1;
    G1.Akw = x_kw; G1.Nkw = NKW; G1.Wk1 = W0; G1.bk = bc1; G1.Zkw = Zkw; G1.Wk2 = W2; G1.Ckw8 = Yb;
    G1.Art = x_rt; G1.Nrt = NRT; G1.Wr1 = W4; G1.br = bl1c; G1.Zrt = Zrt;
    G1.Wr2 = W1; G1.Crt2 = Ya; G1.Wr3 = W3; G1.Crt3 = Yc;
    G1.kwBlocks = kwB;
    gemm_sort_k<<<kwB + rtB + nsort, 256, 0, stream>>>(G1, R, kwB + rtB);

    AggJob JK1 = {Zkw, NKW, sp_a, goff_a, invd_a, Ya, 0, sp_b, goff_b, invd_b, Yb, 1, 2,
                  nullptr, kw1_bf};
    AggJob JR1 = {Zrt, NRT, sp_c, goff_c, invd_c, Yc, 0, nullptr, nullptr, nullptr, nullptr, 0, 1,
                  nullptr, rt1_bf};
    bagg2_k<1, 1><<<nb_kw + nb_rt, 512, 0, stream>>>(JK1, JR1, nb_kw);

    // ---- layer 2 ----
    GemmJobs G2;
    G2.Akw = kw1_bf; G2.Nkw = NKW; G2.Wk1 = W5; G2.bk = bc2; G2.Zkw = Zkw; G2.Wk2 = W7; G2.Ckw8 = Yb;
    G2.Art = rt1_bf; G2.Nrt = NRT; G2.Wr1 = W9; G2.br = bl2c; G2.Zrt = Zrt;
    G2.Wr2 = W6; G2.Crt2 = Ya; G2.Wr3 = W8; G2.Crt3 = Yc;
    G2.kwBlocks = kwB;
    gemm_l2_k<<<kwB + rtB, 256, 0, stream>>>(G2);

    AggJob JK2 = {Zkw, NKW, sp_a, goff_a, invd_a, Ya, 0, sp_b, goff_b, invd_b, Yb, 1, 2,
                  out_kw, nullptr};
    AggJob JR2 = {Zrt, NRT, sp_c, goff_c, invd_c, Yc, 0, nullptr, nullptr, nullptr, nullptr, 0, 1,
                  out_rt, nullptr};
    bagg2_k<0, 0><<<nb_kw + nb_rt, 512, 0, stream>>>(JK2, JR2, nb_kw);
}

// Round 10
// 606.624 us; speedup vs baseline: 1.1041x; 1.1041x over previous
//
#include <hip/hip_runtime.h>

typedef __attribute__((ext_vector_type(8))) short bf16x8;
typedef __attribute__((ext_vector_type(4))) float f32x4;
typedef __attribute__((ext_vector_type(2))) float f32x2;

static __device__ __forceinline__ unsigned short f2bf(float f) {
    unsigned int u = __float_as_uint(f);
    u += 0x7fffu + ((u >> 16) & 1u);   // round-to-nearest-even
    return (unsigned short)(u >> 16);
}
static __device__ __forceinline__ float bf2f(unsigned short h) {
    return __uint_as_float(((unsigned int)h) << 16);
}

#define BSH 6
#define BUCKET 64
#define NBMAX 1600
#define CHSH 13

// ---------------- structs ----------------

struct Rel {
    const int* src; const int* dst; int E; int nb; int Ndst;
    int hblk0, hnblk;
    int sblk0, snblk;
    int oblk0;
    int shift;                 // ssrc stores (s << shift) byte offsets
    int* bcnt; int* boff; int* bcur;
    unsigned* pairs; unsigned* ssrc; int* goff; float* invd;
};
struct Rels { Rel r[3]; };

struct PrepArgs {
    const float* W[10];
    const float* Wa[10];
    const float* b1a; const float* b1b; const float* b2a; const float* b2b;
};

// ---------------- prep + bucket-hist (merged) ----------------

__global__ void prep_hist_k(PrepArgs pa, unsigned short* __restrict__ Wt,
                            float* __restrict__ bc1, float* __restrict__ bc2,
                            Rels R, int prepBlocks) {
    int bid = blockIdx.x;
    if (bid < prepBlocks) {
        if (bid < 640) {
            int slot = bid >> 6;
            int i = ((bid & 63) << 8) + threadIdx.x;
            float v = pa.W[slot][i];
            const float* w2 = pa.Wa[slot];
            if (w2) v += w2[i];
            int k = i >> 7, n = i & 127;
            Wt[slot * 16384 + n * 128 + k] = f2bf(v);
        } else {
            int t = threadIdx.x;
            if (t < 128) bc1[t] = pa.b1a[t] + pa.b1b[t];
            else bc2[t - 128] = pa.b2a[t - 128] + pa.b2b[t - 128];
        }
        return;
    }
    int hb = bid - prepBlocks;
    const Rel* r;
    if (hb < R.r[1].hblk0) r = &R.r[0];
    else if (hb < R.r[2].hblk0) r = &R.r[1];
    else r = &R.r[2];
    __shared__ int h[NBMAX];
    for (int i = threadIdx.x; i < r->nb; i += 256) h[i] = 0;
    __syncthreads();
    for (int e = (hb - r->hblk0) * 256 + threadIdx.x; e < r->E; e += r->hnblk * 256)
        atomicAdd(&h[r->dst[e] >> BSH], 1);
    __syncthreads();
    for (int i = threadIdx.x; i < r->nb; i += 256)
        if (h[i]) atomicAdd(&r->bcnt[i], h[i]);
}

// ---------------- scan + scatter ----------------

__global__ void bscan3_k(Rels R) {
    const Rel* r = &R.r[blockIdx.x];
    __shared__ int s[1024];
    int t = threadIdx.x;
    int nb = r->nb;
    int e0 = 2 * t, e1 = 2 * t + 1;
    int v0 = (e0 < nb) ? r->bcnt[e0] : 0;
    int v1 = (e1 < nb) ? r->bcnt[e1] : 0;
    s[t] = v0 + v1;
    __syncthreads();
    for (int o = 1; o < 1024; o <<= 1) {
        int x = (t >= o) ? s[t - o] : 0;
        __syncthreads();
        s[t] += x;
        __syncthreads();
    }
    int P = s[t] - (v0 + v1);
    if (e0 <= nb) { r->boff[e0] = P; if (e0 < nb) r->bcur[e0] = 0; }
    if (e1 <= nb) { r->boff[e1] = P + v0; if (e1 < nb) r->bcur[e1] = 0; }
}

__global__ __launch_bounds__(256) void bscatter3_k(Rels R) {
    const Rel* r;
    int bid = blockIdx.x;
    if (bid < R.r[1].sblk0) r = &R.r[0];
    else if (bid < R.r[2].sblk0) r = &R.r[1];
    else r = &R.r[2];
    __shared__ int h[NBMAX];
    __shared__ int base[NBMAX];
    int t = threadIdx.x;
    int nb = r->nb, E = r->E;
    for (int i = t; i < nb; i += 256) h[i] = 0;
    __syncthreads();
    int e0 = (bid - r->sblk0) * 8192;
    for (int i = 0; i < 32; i++) {
        int e = e0 + i * 256 + t;
        if (e < E) atomicAdd(&h[r->dst[e] >> BSH], 1);
    }
    __syncthreads();
    for (int i = t; i < nb; i += 256) {
        int c = h[i];
        base[i] = c ? (r->boff[i] + atomicAdd(&r->bcur[i], c)) : 0;
    }
    __syncthreads();
    for (int i = t; i < nb; i += 256) h[i] = 0;
    __syncthreads();
    for (int i = 0; i < 32; i++) {
        int e = e0 + i * 256 + t;
        if (e < E) {
            int d = r->dst[e];
            int b = d >> BSH;
            int pos = base[b] + atomicAdd(&h[b], 1);
            r->pairs[pos] = ((unsigned)(d & (BUCKET - 1)) << 17) | (unsigned)r->src[e];
        }
    }
}

// ---------------- per-bucket counting sort (device body) ----------------
// bin = ((d&7)<<7) | ((d>>3)<<4) | ch; run (16 bins) = (wave w=d&7, row r=d>>3).
static __device__ void sortb_body(const Rels& R, int bid) {
    const Rel* r;
    if (bid < R.r[1].oblk0) r = &R.r[0];
    else if (bid < R.r[2].oblk0) r = &R.r[1];
    else r = &R.r[2];
    int b = bid - r->oblk0;
    __shared__ int cnt[1024];
    __shared__ int sc[256];
    int t = threadIdx.x;
    for (int i = t; i < 1024; i += 256) cnt[i] = 0;
    __syncthreads();
    int j0 = r->boff[b], j1 = r->boff[b + 1];
    for (int j = j0 + t; j < j1; j += 256) {
        unsigned p = r->pairs[j];
        int d = (p >> 17) & 63;
        int ch = (int)((p & 0x1ffffu) >> CHSH); if (ch > 15) ch = 15;
        int bin = ((d & 7) << 7) | ((d >> 3) << 4) | ch;
        atomicAdd(&cnt[bin], 1);
    }
    __syncthreads();
    if (t < 64) {
        int b0 = ((t & 7) << 7) | ((t >> 3) << 4);
        int c = 0;
#pragma unroll
        for (int i = 0; i < 16; i++) c += cnt[b0 + i];
        int dd = (b << BSH) + t;
        if (dd < r->Ndst) r->invd[dd] = 1.f / (float)(c > 0 ? c : 1);
    }
    int c0 = cnt[4 * t], c1 = cnt[4 * t + 1], c2 = cnt[4 * t + 2], c3 = cnt[4 * t + 3];
    int tot = c0 + c1 + c2 + c3;
    sc[t] = tot;
    __syncthreads();
    for (int o = 1; o < 256; o <<= 1) {
        int x = (t >= o) ? sc[t - o] : 0;
        __syncthreads();
        sc[t] += x;
        __syncthreads();
    }
    int base = j0 + sc[t] - tot;
    if ((t & 3) == 0) r->goff[b * 64 + (t >> 2)] = base;
    cnt[4 * t] = base;
    cnt[4 * t + 1] = base + c0;
    cnt[4 * t + 2] = base + c0 + c1;
    cnt[4 * t + 3] = base + c0 + c1 + c2;
    if (t == 0 && b == r->nb - 1) r->goff[r->nb * 64] = r->E;
    __syncthreads();
    int shift = r->shift;
    for (int j = j0 + t; j < j1; j += 256) {
        unsigned p = r->pairs[j];
        int d = (p >> 17) & 63;
        int ch = (int)((p & 0x1ffffu) >> CHSH); if (ch > 15) ch = 15;
        int bin = ((d & 7) << 7) | ((d >> 3) << 4) | ch;
        int pos = atomicAdd(&cnt[bin], 1);
        r->ssrc[pos] = (p & 0x1ffffu) << shift;
    }
}

// ---------------- MFMA GEMM body ----------------

struct GemmJobs {
    const void* Akw; int Nkw;
    const unsigned short* Wk1; const float* bk; unsigned short* Zkw;
    const unsigned short* Wk2; unsigned char* Ckw8;
    const void* Art; int Nrt;
    const unsigned short* Wr1; const float* br; unsigned short* Zrt;
    const unsigned short* Wr2; unsigned short* Crt2;
    const unsigned short* Wr3; unsigned short* Crt3;
    int kwBlocks;
};

template <int AF32>
static __device__ void gemm_body(const GemmJobs& G, int bid) {
    bool iskw = bid < G.kwBlocks;
    const void* A = iskw ? G.Akw : G.Art;
    int N = iskw ? G.Nkw : G.Nrt;
    int lane = threadIdx.x & 63;
    int r16 = lane & 15, g = lane >> 4;
    int row0 = (iskw ? bid : bid - G.kwBlocks) * 64 + (threadIdx.x >> 6) * 16;
    int arow = row0 + r16;
    int arow_c = arow < N ? arow : N - 1;

    bf16x8 af[4];
    if (AF32) {
        const float* Af = (const float*)A + (size_t)arow_c * 128 + g * 8;
#pragma unroll
        for (int kc = 0; kc < 4; kc++) {
            float4 u0 = *(const float4*)(Af + kc * 32);
            float4 u1 = *(const float4*)(Af + kc * 32 + 4);
            bf16x8 rr;
            rr[0] = (short)f2bf(u0.x); rr[1] = (short)f2bf(u0.y);
            rr[2] = (short)f2bf(u0.z); rr[3] = (short)f2bf(u0.w);
            rr[4] = (short)f2bf(u1.x); rr[5] = (short)f2bf(u1.y);
            rr[6] = (short)f2bf(u1.z); rr[7] = (short)f2bf(u1.w);
            af[kc] = rr;
        }
    } else {
        const bf16x8* Ar = (const bf16x8*)((const unsigned short*)A + (size_t)arow_c * 128);
#pragma unroll
        for (int kc = 0; kc < 4; kc++) af[kc] = Ar[kc * 4 + g];
    }

    if (iskw) {
        f32x4 acc1[8], acc2[8];
#pragma unroll
        for (int ct = 0; ct < 8; ct++) { f32x4 z = {0.f,0.f,0.f,0.f}; acc1[ct] = z; acc2[ct] = z; }
#pragma unroll
        for (int kc = 0; kc < 4; kc++) {
#pragma unroll
            for (int ct = 0; ct < 8; ct++) {
                int wo = ((ct * 16 + r16) << 7) + kc * 32 + g * 8;
                bf16x8 b1 = *(const bf16x8*)(G.Wk1 + wo);
                acc1[ct] = __builtin_amdgcn_mfma_f32_16x16x32_bf16(af[kc], b1, acc1[ct], 0, 0, 0);
                bf16x8 b2 = *(const bf16x8*)(G.Wk2 + wo);
                acc2[ct] = __builtin_amdgcn_mfma_f32_16x16x32_bf16(af[kc], b2, acc2[ct], 0, 0, 0);
            }
        }
#pragma unroll
        for (int ct = 0; ct < 8; ct++) {
            int col = ct * 16 + r16;
            float bb = G.bk[col];
#pragma unroll
            for (int j = 0; j < 4; j++) {
                int r = row0 + g * 4 + j;
                if (r < N) {
                    G.Zkw[(size_t)r * 128 + col] = f2bf(acc1[ct][j] + bb);
                    float v2 = acc2[ct][j];
                    int pk = __builtin_amdgcn_cvt_pk_fp8_f32(v2, v2, 0, false);
                    G.Ckw8[(size_t)r * 128 + col] = (unsigned char)(pk & 0xff);
                }
            }
        }
    } else {
        f32x4 acc1[8], acc2[8], acc3[8];
#pragma unroll
        for (int ct = 0; ct < 8; ct++) {
            f32x4 z = {0.f,0.f,0.f,0.f}; acc1[ct] = z; acc2[ct] = z; acc3[ct] = z;
        }
#pragma unroll
        for (int kc = 0; kc < 4; kc++) {
#pragma unroll
            for (int ct = 0; ct < 8; ct++) {
                int wo = ((ct * 16 + r16) << 7) + kc * 32 + g * 8;
                bf16x8 b1 = *(const bf16x8*)(G.Wr1 + wo);
                acc1[ct] = __builtin_amdgcn_mfma_f32_16x16x32_bf16(af[kc], b1, acc1[ct], 0, 0, 0);
                bf16x8 b2 = *(const bf16x8*)(G.Wr2 + wo);
                acc2[ct] = __builtin_amdgcn_mfma_f32_16x16x32_bf16(af[kc], b2, acc2[ct], 0, 0, 0);
                bf16x8 b3 = *(const bf16x8*)(G.Wr3 + wo);
                acc3[ct] = __builtin_amdgcn_mfma_f32_16x16x32_bf16(af[kc], b3, acc3[ct], 0, 0, 0);
            }
        }
#pragma unroll
        for (int ct = 0; ct < 8; ct++) {
            int col = ct * 16 + r16;
            float bb = G.br[col];
#pragma unroll
            for (int j = 0; j < 4; j++) {
                int r = row0 + g * 4 + j;
                if (r < N) {
                    G.Zrt[(size_t)r * 128 + col] = f2bf(acc1[ct][j] + bb);
                    G.Crt2[(size_t)r * 128 + col] = f2bf(acc2[ct][j]);
                    G.Crt3[(size_t)r * 128 + col] = f2bf(acc3[ct][j]);
                }
            }
        }
    }
}

__global__ __launch_bounds__(256) void gemm_sort_k(GemmJobs G, Rels R, int gemmBlocks) {
    if ((int)blockIdx.x < gemmBlocks) gemm_body<1>(G, blockIdx.x);
    else sortb_body(R, blockIdx.x - gemmBlocks);
}

__global__ __launch_bounds__(256) void gemm_l2_k(GemmJobs G) {
    gemm_body<0>(G, blockIdx.x);
}

// ---------------- register-only bucket aggregation ----------------
// Block = one 64-dst bucket, 8 waves, NO LDS. Wave w owns rows d=(r<<3)|w,
// exclusively across both relations. Per edge: 16-lane group g=lane>>4, lane q
// covers features 8q..8q+7 via one uint4 (bf16) / uint2 (fp8) -> 4 edges per
// VMEM inst. Raw sums scaled per relation in-lane (commutes with lane reduce),
// one shfl_xor(16/32) reduce per row, Z added from registers, direct global
// store (group-predicated, coalesced). Zero LDS, zero barriers.
template <int FMT>   // 0: bf16 rows, 1: fp8 rows
static __device__ __forceinline__ void row_accum(const unsigned* __restrict__ sp,
                                                 int jg0, int jg1,
                                                 const char* __restrict__ Y, int lb, int g,
                                                 f32x2& a01, f32x2& a23,
                                                 f32x2& a45, f32x2& a67) {
#pragma unroll 1
    for (int jb = jg0; jb < jg1; jb += 16) {
        if (jb + 16 <= jg1) {
            unsigned o0 = sp[jb + g], o1 = sp[jb + 4 + g];
            unsigned o2 = sp[jb + 8 + g], o3 = sp[jb + 12 + g];
            if (FMT == 0) {
                uint4 v0 = *(const uint4*)(Y + o0 + lb);
                uint4 v1 = *(const uint4*)(Y + o1 + lb);
                uint4 v2 = *(const uint4*)(Y + o2 + lb);
                uint4 v3 = *(const uint4*)(Y + o3 + lb);
#pragma unroll
                for (int k = 0; k < 4; k++) {
                    uint4 v = k == 0 ? v0 : k == 1 ? v1 : k == 2 ? v2 : v3;
                    f32x2 x0 = { __uint_as_float(v.x << 16), __uint_as_float(v.x & 0xffff0000u) };
                    f32x2 x1 = { __uint_as_float(v.y << 16), __uint_as_float(v.y & 0xffff0000u) };
                    f32x2 x2 = { __uint_as_float(v.z << 16), __uint_as_float(v.z & 0xffff0000u) };
                    f32x2 x3 = { __uint_as_float(v.w << 16), __uint_as_float(v.w & 0xffff0000u) };
                    a01 += x0; a23 += x1; a45 += x2; a67 += x3;
                }
            } else {
                uint2 v0 = *(const uint2*)(Y + o0 + lb);
                uint2 v1 = *(const uint2*)(Y + o1 + lb);
                uint2 v2 = *(const uint2*)(Y + o2 + lb);
                uint2 v3 = *(const uint2*)(Y + o3 + lb);
#pragma unroll
                for (int k = 0; k < 4; k++) {
                    uint2 v = k == 0 ? v0 : k == 1 ? v1 : k == 2 ? v2 : v3;
                    auto l0 = __builtin_amdgcn_cvt_pk_f32_fp8(v.x, false);
                    auto h0 = __builtin_amdgcn_cvt_pk_f32_fp8(v.x, true);
                    auto l1 = __builtin_amdgcn_cvt_pk_f32_fp8(v.y, false);
                    auto h1 = __builtin_amdgcn_cvt_pk_f32_fp8(v.y, true);
                    a01[0] += l0[0]; a01[1] += l0[1];
                    a23[0] += h0[0]; a23[1] += h0[1];
                    a45[0] += l1[0]; a45[1] += l1[1];
                    a67[0] += h1[0]; a67[1] += h1[1];
                }
            }
        } else {   // tail <16 edges, predicated
#pragma unroll
            for (int k = 0; k < 4; k++) {
                int e = jb + 4 * k + g;
                int ec = e < jg1 ? e : jg1 - 1;
                bool live = e < jg1;
                unsigned o = sp[ec];
                if (FMT == 0) {
                    uint4 v = *(const uint4*)(Y + o + lb);
                    unsigned vx = live ? v.x : 0u, vy = live ? v.y : 0u;
                    unsigned vz = live ? v.z : 0u, vw = live ? v.w : 0u;
                    f32x2 x0 = { __uint_as_float(vx << 16), __uint_as_float(vx & 0xffff0000u) };
                    f32x2 x1 = { __uint_as_float(vy << 16), __uint_as_float(vy & 0xffff0000u) };
                    f32x2 x2 = { __uint_as_float(vz << 16), __uint_as_float(vz & 0xffff0000u) };
                    f32x2 x3 = { __uint_as_float(vw << 16), __uint_as_float(vw & 0xffff0000u) };
                    a01 += x0; a23 += x1; a45 += x2; a67 += x3;
                } else {
                    uint2 v = *(const uint2*)(Y + o + lb);
                    unsigned vx = live ? v.x : 0u, vy = live ? v.y : 0u;
                    auto l0 = __builtin_amdgcn_cvt_pk_f32_fp8(vx, false);
                    auto h0 = __builtin_amdgcn_cvt_pk_f32_fp8(vx, true);
                    auto l1 = __builtin_amdgcn_cvt_pk_f32_fp8(vy, false);
                    auto h1 = __builtin_amdgcn_cvt_pk_f32_fp8(vy, true);
                    a01[0] += l0[0]; a01[1] += l0[1];
                    a23[0] += h0[0]; a23[1] += h0[1];
                    a45[0] += l1[0]; a45[1] += l1[1];
                    a67[0] += h1[0]; a67[1] += h1[1];
                }
            }
        }
    }
}

struct AggJob {
    const unsigned short* Zin; int Ndst;
    const unsigned* sp0; const int* goff0; const float* invd0; const void* Y0; int fmt0;
    const unsigned* sp1; const int* goff1; const float* invd1; const void* Y1; int fmt1;
    int nrel;
    float* OutF; unsigned short* OutB;
};

template <int RELU, int OUTBF16>
__global__ __launch_bounds__(512) void bagg3_k(AggJob JK, AggJob JR, int kwBlocks) {
    bool iskw = blockIdx.x < (unsigned)kwBlocks;
    AggJob J = iskw ? JK : JR;
    int b = iskw ? blockIdx.x : blockIdx.x - kwBlocks;
    int dst0 = b << BSH;
    int t = threadIdx.x;
    int w = t >> 6, lane = t & 63;
    int g = lane >> 4, q = lane & 15;
    int lb0 = J.fmt0 ? (q << 3) : (q << 4);
    int lb1 = J.fmt1 ? (q << 3) : (q << 4);

#pragma unroll 1
    for (int r = 0; r < 8; r++) {
        int d = (r << 3) | w;
        if (dst0 + d >= J.Ndst) continue;
        int gi = b * 64 + w * 8 + r;
        // relation 0
        f32x2 a01 = {0.f,0.f}, a23 = {0.f,0.f}, a45 = {0.f,0.f}, a67 = {0.f,0.f};
        {
            int jg0 = J.goff0[gi], jg1 = J.goff0[gi + 1];
            if (J.fmt0 == 0) row_accum<0>(J.sp0, jg0, jg1, (const char*)J.Y0, lb0, g, a01, a23, a45, a67);
            else             row_accum<1>(J.sp0, jg0, jg1, (const char*)J.Y0, lb0, g, a01, a23, a45, a67);
        }
        float inv0 = J.invd0[dst0 + d];
        float r0 = a01[0] * inv0, r1 = a01[1] * inv0;
        float r2 = a23[0] * inv0, r3 = a23[1] * inv0;
        float r4 = a45[0] * inv0, r5 = a45[1] * inv0;
        float r6 = a67[0] * inv0, r7 = a67[1] * inv0;
        if (J.nrel == 2) {
            f32x2 b01 = {0.f,0.f}, b23 = {0.f,0.f}, b45 = {0.f,0.f}, b67 = {0.f,0.f};
            int jg0 = J.goff1[gi], jg1 = J.goff1[gi + 1];
            if (J.fmt1 == 0) row_accum<0>(J.sp1, jg0, jg1, (const char*)J.Y1, lb1, g, b01, b23, b45, b67);
            else             row_accum<1>(J.sp1, jg0, jg1, (const char*)J.Y1, lb1, g, b01, b23, b45, b67);
            float inv1 = J.invd1[dst0 + d];
            r0 = fmaf(b01[0], inv1, r0); r1 = fmaf(b01[1], inv1, r1);
            r2 = fmaf(b23[0], inv1, r2); r3 = fmaf(b23[1], inv1, r3);
            r4 = fmaf(b45[0], inv1, r4); r5 = fmaf(b45[1], inv1, r5);
            r6 = fmaf(b67[0], inv1, r6); r7 = fmaf(b67[1], inv1, r7);
        }
        // reduce across the 4 groups (same features, different edges)
        r0 += __shfl_xor(r0, 16); r0 += __shfl_xor(r0, 32);
        r1 += __shfl_xor(r1, 16); r1 += __shfl_xor(r1, 32);
        r2 += __shfl_xor(r2, 16); r2 += __shfl_xor(r2, 32);
        r3 += __shfl_xor(r3, 16); r3 += __shfl_xor(r3, 32);
        r4 += __shfl_xor(r4, 16); r4 += __shfl_xor(r4, 32);
        r5 += __shfl_xor(r5, 16); r5 += __shfl_xor(r5, 32);
        r6 += __shfl_xor(r6, 16); r6 += __shfl_xor(r6, 32);
        r7 += __shfl_xor(r7, 16); r7 += __shfl_xor(r7, 32);
        // add Z (bf16 row, features 8q..8q+7)
        uint4 zz = *(const uint4*)((const char*)J.Zin + (((size_t)(dst0 + d)) << 8) + (q << 4));
        r0 += __uint_as_float(zz.x << 16); r1 += __uint_as_float(zz.x & 0xffff0000u);
        r2 += __uint_as_float(zz.y << 16); r3 += __uint_as_float(zz.y & 0xffff0000u);
        r4 += __uint_as_float(zz.z << 16); r5 += __uint_as_float(zz.z & 0xffff0000u);
        r6 += __uint_as_float(zz.w << 16); r7 += __uint_as_float(zz.w & 0xffff0000u);
        if (RELU) {
            r0 = fmaxf(r0, 0.f); r1 = fmaxf(r1, 0.f); r2 = fmaxf(r2, 0.f); r3 = fmaxf(r3, 0.f);
            r4 = fmaxf(r4, 0.f); r5 = fmaxf(r5, 0.f); r6 = fmaxf(r6, 0.f); r7 = fmaxf(r7, 0.f);
        }
        if (OUTBF16) {
            if (g == 0) {
                uint4 ov;
                ov.x = (unsigned)f2bf(r0) | ((unsigned)f2bf(r1) << 16);
                ov.y = (unsigned)f2bf(r2) | ((unsigned)f2bf(r3) << 16);
                ov.z = (unsigned)f2bf(r4) | ((unsigned)f2bf(r5) << 16);
                ov.w = (unsigned)f2bf(r6) | ((unsigned)f2bf(r7) << 16);
                *(uint4*)((char*)J.OutB + (((size_t)(dst0 + d)) << 8) + (q << 4)) = ov;
            }
        } else {
            float* orow = J.OutF + ((size_t)(dst0 + d) << 7) + (q << 3);
            if (g == 0) *(float4*)orow = make_float4(r0, r1, r2, r3);
            if (g == 1) *(float4*)(orow + 4) = make_float4(r4, r5, r6, r7);
        }
    }
}

// ---------------- launch ----------------

static inline size_t align256(size_t x) { return (x + 255) & ~size_t(255); }

extern "C" void kernel_launch(void* const* d_in, const int* in_sizes, int n_in,
                              void* d_out, int out_size, void* d_ws, size_t ws_size,
                              hipStream_t stream) {
    const float* x_kw = (const float*)d_in[0];
    const float* x_rt = (const float*)d_in[1];
    const int* src_a = (const int*)d_in[2];
    const int* dst_a = (const int*)d_in[3];
    const int* src_b = (const int*)d_in[4];
    const int* dst_b = (const int*)d_in[5];
    const int* src_c = (const int*)d_in[6];
    const int* dst_c = (const int*)d_in[7];
    const float *Wl1a = (const float*)d_in[8],  *bl1a = (const float*)d_in[9],  *Wr1a = (const float*)d_in[10];
    const float *Wl1b = (const float*)d_in[11], *bl1b = (const float*)d_in[12], *Wr1b = (const float*)d_in[13];
    const float *Wl1c = (const float*)d_in[14], *bl1c = (const float*)d_in[15], *Wr1c = (const float*)d_in[16];
    const float *Wl2a = (const float*)d_in[17], *bl2a = (const float*)d_in[18], *Wr2a = (const float*)d_in[19];
    const float *Wl2b = (const float*)d_in[20], *bl2b = (const float*)d_in[21], *Wr2b = (const float*)d_in[22];
    const float *Wl2c = (const float*)d_in[23], *bl2c = (const float*)d_in[24], *Wr2c = (const float*)d_in[25];

    const int NKW = in_sizes[0] / 128;
    const int NRT = in_sizes[1] / 128;
    const int EA = in_sizes[2], EB = in_sizes[4], EC = in_sizes[6];
    const int nb_kw = (NKW + BUCKET - 1) / BUCKET;
    const int nb_rt = (NRT + BUCKET - 1) / BUCKET;

    char* ws = (char*)d_ws;
    size_t off = 0;
    auto alloc = [&](size_t bytes) -> char* {
        off = align256(off);
        char* p = ws + off;
        off += bytes;
        return p;
    };
    unsigned short* Wt = (unsigned short*)alloc(10 * 16384 * 2);
    float* bc1 = (float*)alloc(128 * 4);
    float* bc2 = (float*)alloc(128 * 4);
    int* bcnt3 = (int*)alloc(3 * NBMAX * 4);
    int* bcur3 = (int*)alloc(3 * NBMAX * 4);
    int* boff_a = (int*)alloc((NBMAX + 1) * 4);
    int* boff_b = (int*)alloc((NBMAX + 1) * 4);
    int* boff_c = (int*)alloc((NBMAX + 1) * 4);
    int* goff_a = (int*)alloc(((size_t)nb_kw * 64 + 1) * 4);
    int* goff_b = (int*)alloc(((size_t)nb_kw * 64 + 1) * 4);
    int* goff_c = (int*)alloc(((size_t)nb_rt * 64 + 1) * 4);
    float* invd_a = (float*)alloc((size_t)NKW * 4);
    float* invd_b = (float*)alloc((size_t)NKW * 4);
    float* invd_c = (float*)alloc((size_t)NRT * 4);
    unsigned* pairs_a = (unsigned*)alloc((size_t)EA * 4);
    unsigned* pairs_b = (unsigned*)alloc((size_t)EB * 4);
    unsigned* pairs_c = (unsigned*)alloc((size_t)EC * 4);
    unsigned* sp_a = (unsigned*)alloc((size_t)EA * 4);
    unsigned* sp_b = (unsigned*)alloc((size_t)EB * 4);
    unsigned* sp_c = (unsigned*)alloc((size_t)EC * 4);
    unsigned short* Ya = (unsigned short*)alloc((size_t)NRT * 128 * 2);
    unsigned char*  Yb = (unsigned char*)alloc((size_t)NKW * 128);      // fp8
    unsigned short* Yc = (unsigned short*)alloc((size_t)NRT * 128 * 2);
    unsigned short* Zkw = (unsigned short*)alloc((size_t)NKW * 128 * 2);
    unsigned short* Zrt = (unsigned short*)alloc((size_t)NRT * 128 * 2);
    unsigned short* kw1_bf = (unsigned short*)alloc((size_t)NKW * 128 * 2);
    unsigned short* rt1_bf = (unsigned short*)alloc((size_t)NRT * 128 * 2);
    (void)ws_size;

    float* out_kw = (float*)d_out;
    float* out_rt = out_kw + (size_t)NKW * 128;

    // ---- Rels ----
    Rels R;
    int hA = 128, hB = 128, hC = 64;
    int sA = (EA + 8191) / 8192, sB = (EB + 8191) / 8192, sC = (EC + 8191) / 8192;
    R.r[0] = {src_a, dst_a, EA, nb_kw, NKW, 0, hA, 0, sA, 0, 8,
              bcnt3, boff_a, bcur3, pairs_a, sp_a, goff_a, invd_a};
    R.r[1] = {src_b, dst_b, EB, nb_kw, NKW, hA, hB, sA, sB, nb_kw, 7,   // fp8 rows: 128 B
              bcnt3 + NBMAX, boff_b, bcur3 + NBMAX, pairs_b, sp_b, goff_b, invd_b};
    R.r[2] = {src_c, dst_c, EC, nb_rt, NRT, hA + hB, hC, sA + sB, sC, 2 * nb_kw, 8,
              bcnt3 + 2 * NBMAX, boff_c, bcur3 + 2 * NBMAX, pairs_c, sp_c, goff_c, invd_c};

    // ---- prep + hist ----
    hipMemsetAsync(bcnt3, 0, 3 * NBMAX * 4, stream);
    PrepArgs pa;
    pa.W[0] = Wr1a; pa.Wa[0] = Wr1b;
    pa.W[1] = Wl1a; pa.Wa[1] = nullptr;
    pa.W[2] = Wl1b; pa.Wa[2] = nullptr;
    pa.W[3] = Wl1c; pa.Wa[3] = nullptr;
    pa.W[4] = Wr1c; pa.Wa[4] = nullptr;
    pa.W[5] = Wr2a; pa.Wa[5] = Wr2b;
    pa.W[6] = Wl2a; pa.Wa[6] = nullptr;
    pa.W[7] = Wl2b; pa.Wa[7] = nullptr;
    pa.W[8] = Wl2c; pa.Wa[8] = nullptr;
    pa.W[9] = Wr2c; pa.Wa[9] = nullptr;
    pa.b1a = bl1a; pa.b1b = bl1b; pa.b2a = bl2a; pa.b2b = bl2b;
    prep_hist_k<<<641 + hA + hB + hC, 256, 0, stream>>>(pa, Wt, bc1, bc2, R, 641);
    unsigned short* W0 = Wt + 0 * 16384;
    unsigned short* W1 = Wt + 1 * 16384;
    unsigned short* W2 = Wt + 2 * 16384;
    unsigned short* W3 = Wt + 3 * 16384;
    unsigned short* W4 = Wt + 4 * 16384;
    unsigned short* W5 = Wt + 5 * 16384;
    unsigned short* W6 = Wt + 6 * 16384;
    unsigned short* W7 = Wt + 7 * 16384;
    unsigned short* W8 = Wt + 8 * 16384;
    unsigned short* W9 = Wt + 9 * 16384;

    bscan3_k<<<3, 1024, 0, stream>>>(R);
    bscatter3_k<<<sA + sB + sC, 256, 0, stream>>>(R);

    const int kwB = (NKW + 63) / 64, rtB = (NRT + 63) / 64;
    const int nsort = 2 * nb_kw + nb_rt;

    // ---- layer 1: gemms + bucket sort in one launch (independent) ----
    GemmJobs G1;
    G1.Akw = x_kw; G1.Nkw = NKW; G1.Wk1 = W0; G1.bk = bc1; G1.Zkw = Zkw; G1.Wk2 = W2; G1.Ckw8 = Yb;
    G1.Art = x_rt; G1.Nrt = NRT; G1.Wr1 = W4; G1.br = bl1c; G1.Zrt = Zrt;
    G1.Wr2 = W1; G1.Crt2 = Ya; G1.Wr3 = W3; G1.Crt3 = Yc;
    G1.kwBlocks = kwB;
    gemm_sort_k<<<kwB + rtB + nsort, 256, 0, stream>>>(G1, R, kwB + rtB);

    AggJob JK1 = {Zkw, NKW, sp_a, goff_a, invd_a, Ya, 0, sp_b, goff_b, invd_b, Yb, 1, 2,
                  nullptr, kw1_bf};
    AggJob JR1 = {Zrt, NRT, sp_c, goff_c, invd_c, Yc, 0, nullptr, nullptr, nullptr, nullptr, 0, 1,
                  nullptr, rt1_bf};
    bagg3_k<1, 1><<<nb_kw + nb_rt, 512, 0, stream>>>(JK1, JR1, nb_kw);

    // ---- layer 2 ----
    GemmJobs G2;
    G2.Akw = kw1_bf; G2.Nkw = NKW; G2.Wk1 = W5; G2.bk = bc2; G2.Zkw = Zkw; G2.Wk2 = W7; G2.Ckw8 = Yb;
    G2.Art = rt1_bf; G2.Nrt = NRT; G2.Wr1 = W9; G2.br = bl2c; G2.Zrt = Zrt;
    G2.Wr2 = W6; G2.Crt2 = Ya; G2.Wr3 = W8; G2.Crt3 = Yc;
    G2.kwBlocks = kwB;
    gemm_l2_k<<<kwB + rtB, 256, 0, stream>>>(G2);

    AggJob JK2 = {Zkw, NKW, sp_a, goff_a, invd_a, Ya, 0, sp_b, goff_b, invd_b, Yb, 1, 2,
                  out_kw, nullptr};
    AggJob JR2 = {Zrt, NRT, sp_c, goff_c, invd_c, Yc, 0, nullptr, nullptr, nullptr, nullptr, 0, 1,
                  out_rt, nullptr};
    bagg3_k<0, 0><<<nb_kw + nb_rt, 512, 0, stream>>>(JK2, JR2, nb_kw);
}

// Round 11
// 586.268 us; speedup vs baseline: 1.1424x; 1.0347x over previous
//
#include <hip/hip_runtime.h>

typedef __attribute__((ext_vector_type(8))) short bf16x8;
typedef __attribute__((ext_vector_type(4))) float f32x4;
typedef __attribute__((ext_vector_type(2))) float f32x2;

static __device__ __forceinline__ unsigned short f2bf(float f) {
    unsigned int u = __float_as_uint(f);
    u += 0x7fffu + ((u >> 16) & 1u);   // round-to-nearest-even
    return (unsigned short)(u >> 16);
}
static __device__ __forceinline__ float bf2f(unsigned short h) {
    return __uint_as_float(((unsigned int)h) << 16);
}

#define BSH 6
#define BUCKET 64
#define NBMAX 1600
#define CHSH 13

// ---------------- structs ----------------

struct Rel {
    const int* src; const int* dst; int E; int nb; int Ndst;
    int hblk0, hnblk;
    int sblk0, snblk;
    int oblk0;
    int shift;                 // ssrc stores (s << shift) byte offsets
    int* bcnt; int* boff; int* bcur;
    unsigned* pairs; unsigned* ssrc; int* goff; float* invd;
};
struct Rels { Rel r[3]; };

struct PrepArgs {
    const float* W[10];
    const float* Wa[10];
    const float* b1a; const float* b1b; const float* b2a; const float* b2b;
};

// ---------------- prep + bucket-hist (merged) ----------------

__global__ void prep_hist_k(PrepArgs pa, unsigned short* __restrict__ Wt,
                            float* __restrict__ bc1, float* __restrict__ bc2,
                            Rels R, int prepBlocks) {
    int bid = blockIdx.x;
    if (bid < prepBlocks) {
        if (bid < 640) {
            int slot = bid >> 6;
            int i = ((bid & 63) << 8) + threadIdx.x;
            float v = pa.W[slot][i];
            const float* w2 = pa.Wa[slot];
            if (w2) v += w2[i];
            int k = i >> 7, n = i & 127;
            Wt[slot * 16384 + n * 128 + k] = f2bf(v);
        } else {
            int t = threadIdx.x;
            if (t < 128) bc1[t] = pa.b1a[t] + pa.b1b[t];
            else bc2[t - 128] = pa.b2a[t - 128] + pa.b2b[t - 128];
        }
        return;
    }
    int hb = bid - prepBlocks;
    const Rel* r;
    if (hb < R.r[1].hblk0) r = &R.r[0];
    else if (hb < R.r[2].hblk0) r = &R.r[1];
    else r = &R.r[2];
    __shared__ int h[NBMAX];
    for (int i = threadIdx.x; i < r->nb; i += 256) h[i] = 0;
    __syncthreads();
    for (int e = (hb - r->hblk0) * 256 + threadIdx.x; e < r->E; e += r->hnblk * 256)
        atomicAdd(&h[r->dst[e] >> BSH], 1);
    __syncthreads();
    for (int i = threadIdx.x; i < r->nb; i += 256)
        if (h[i]) atomicAdd(&r->bcnt[i], h[i]);
}

// ---------------- scan + scatter ----------------

__global__ void bscan3_k(Rels R) {
    const Rel* r = &R.r[blockIdx.x];
    __shared__ int s[1024];
    int t = threadIdx.x;
    int nb = r->nb;
    int e0 = 2 * t, e1 = 2 * t + 1;
    int v0 = (e0 < nb) ? r->bcnt[e0] : 0;
    int v1 = (e1 < nb) ? r->bcnt[e1] : 0;
    s[t] = v0 + v1;
    __syncthreads();
    for (int o = 1; o < 1024; o <<= 1) {
        int x = (t >= o) ? s[t - o] : 0;
        __syncthreads();
        s[t] += x;
        __syncthreads();
    }
    int P = s[t] - (v0 + v1);
    if (e0 <= nb) { r->boff[e0] = P; if (e0 < nb) r->bcur[e0] = 0; }
    if (e1 <= nb) { r->boff[e1] = P + v0; if (e1 < nb) r->bcur[e1] = 0; }
}

__global__ __launch_bounds__(256) void bscatter3_k(Rels R) {
    const Rel* r;
    int bid = blockIdx.x;
    if (bid < R.r[1].sblk0) r = &R.r[0];
    else if (bid < R.r[2].sblk0) r = &R.r[1];
    else r = &R.r[2];
    __shared__ int h[NBMAX];
    __shared__ int base[NBMAX];
    int t = threadIdx.x;
    int nb = r->nb, E = r->E;
    for (int i = t; i < nb; i += 256) h[i] = 0;
    __syncthreads();
    int e0 = (bid - r->sblk0) * 8192;
    for (int i = 0; i < 32; i++) {
        int e = e0 + i * 256 + t;
        if (e < E) atomicAdd(&h[r->dst[e] >> BSH], 1);
    }
    __syncthreads();
    for (int i = t; i < nb; i += 256) {
        int c = h[i];
        base[i] = c ? (r->boff[i] + atomicAdd(&r->bcur[i], c)) : 0;
    }
    __syncthreads();
    for (int i = t; i < nb; i += 256) h[i] = 0;
    __syncthreads();
    for (int i = 0; i < 32; i++) {
        int e = e0 + i * 256 + t;
        if (e < E) {
            int d = r->dst[e];
            int b = d >> BSH;
            int pos = base[b] + atomicAdd(&h[b], 1);
            r->pairs[pos] = ((unsigned)(d & (BUCKET - 1)) << 17) | (unsigned)r->src[e];
        }
    }
}

// ---------------- per-bucket counting sort (device body) ----------------
// bin = ((d&7)<<7) | ((d>>3)<<4) | ch; run (16 bins) = (wave w=d&7, row r=d>>3).
static __device__ void sortb_body(const Rels& R, int bid) {
    const Rel* r;
    if (bid < R.r[1].oblk0) r = &R.r[0];
    else if (bid < R.r[2].oblk0) r = &R.r[1];
    else r = &R.r[2];
    int b = bid - r->oblk0;
    __shared__ int cnt[1024];
    __shared__ int sc[256];
    int t = threadIdx.x;
    for (int i = t; i < 1024; i += 256) cnt[i] = 0;
    __syncthreads();
    int j0 = r->boff[b], j1 = r->boff[b + 1];
    for (int j = j0 + t; j < j1; j += 256) {
        unsigned p = r->pairs[j];
        int d = (p >> 17) & 63;
        int ch = (int)((p & 0x1ffffu) >> CHSH); if (ch > 15) ch = 15;
        int bin = ((d & 7) << 7) | ((d >> 3) << 4) | ch;
        atomicAdd(&cnt[bin], 1);
    }
    __syncthreads();
    if (t < 64) {
        int b0 = ((t & 7) << 7) | ((t >> 3) << 4);
        int c = 0;
#pragma unroll
        for (int i = 0; i < 16; i++) c += cnt[b0 + i];
        int dd = (b << BSH) + t;
        if (dd < r->Ndst) r->invd[dd] = 1.f / (float)(c > 0 ? c : 1);
    }
    int c0 = cnt[4 * t], c1 = cnt[4 * t + 1], c2 = cnt[4 * t + 2], c3 = cnt[4 * t + 3];
    int tot = c0 + c1 + c2 + c3;
    sc[t] = tot;
    __syncthreads();
    for (int o = 1; o < 256; o <<= 1) {
        int x = (t >= o) ? sc[t - o] : 0;
        __syncthreads();
        sc[t] += x;
        __syncthreads();
    }
    int base = j0 + sc[t] - tot;
    if ((t & 3) == 0) r->goff[b * 64 + (t >> 2)] = base;
    cnt[4 * t] = base;
    cnt[4 * t + 1] = base + c0;
    cnt[4 * t + 2] = base + c0 + c1;
    cnt[4 * t + 3] = base + c0 + c1 + c2;
    if (t == 0 && b == r->nb - 1) r->goff[r->nb * 64] = r->E;
    __syncthreads();
    int shift = r->shift;
    for (int j = j0 + t; j < j1; j += 256) {
        unsigned p = r->pairs[j];
        int d = (p >> 17) & 63;
        int ch = (int)((p & 0x1ffffu) >> CHSH); if (ch > 15) ch = 15;
        int bin = ((d & 7) << 7) | ((d >> 3) << 4) | ch;
        int pos = atomicAdd(&cnt[bin], 1);
        r->ssrc[pos] = (p & 0x1ffffu) << shift;
    }
}

// ---------------- MFMA GEMM body ----------------

struct GemmJobs {
    const void* Akw; int Nkw;
    const unsigned short* Wk1; const float* bk; unsigned short* Zkw;
    const unsigned short* Wk2; unsigned char* Ckw8;
    const void* Art; int Nrt;
    const unsigned short* Wr1; const float* br; unsigned short* Zrt;
    const unsigned short* Wr2; unsigned short* Crt2;
    const unsigned short* Wr3; unsigned short* Crt3;
    int kwBlocks;
};

template <int AF32>
static __device__ void gemm_body(const GemmJobs& G, int bid) {
    bool iskw = bid < G.kwBlocks;
    const void* A = iskw ? G.Akw : G.Art;
    int N = iskw ? G.Nkw : G.Nrt;
    int lane = threadIdx.x & 63;
    int r16 = lane & 15, g = lane >> 4;
    int row0 = (iskw ? bid : bid - G.kwBlocks) * 64 + (threadIdx.x >> 6) * 16;
    int arow = row0 + r16;
    int arow_c = arow < N ? arow : N - 1;

    bf16x8 af[4];
    if (AF32) {
        const float* Af = (const float*)A + (size_t)arow_c * 128 + g * 8;
#pragma unroll
        for (int kc = 0; kc < 4; kc++) {
            float4 u0 = *(const float4*)(Af + kc * 32);
            float4 u1 = *(const float4*)(Af + kc * 32 + 4);
            bf16x8 rr;
            rr[0] = (short)f2bf(u0.x); rr[1] = (short)f2bf(u0.y);
            rr[2] = (short)f2bf(u0.z); rr[3] = (short)f2bf(u0.w);
            rr[4] = (short)f2bf(u1.x); rr[5] = (short)f2bf(u1.y);
            rr[6] = (short)f2bf(u1.z); rr[7] = (short)f2bf(u1.w);
            af[kc] = rr;
        }
    } else {
        const bf16x8* Ar = (const bf16x8*)((const unsigned short*)A + (size_t)arow_c * 128);
#pragma unroll
        for (int kc = 0; kc < 4; kc++) af[kc] = Ar[kc * 4 + g];
    }

    if (iskw) {
        f32x4 acc1[8], acc2[8];
#pragma unroll
        for (int ct = 0; ct < 8; ct++) { f32x4 z = {0.f,0.f,0.f,0.f}; acc1[ct] = z; acc2[ct] = z; }
#pragma unroll
        for (int kc = 0; kc < 4; kc++) {
#pragma unroll
            for (int ct = 0; ct < 8; ct++) {
                int wo = ((ct * 16 + r16) << 7) + kc * 32 + g * 8;
                bf16x8 b1 = *(const bf16x8*)(G.Wk1 + wo);
                acc1[ct] = __builtin_amdgcn_mfma_f32_16x16x32_bf16(af[kc], b1, acc1[ct], 0, 0, 0);
                bf16x8 b2 = *(const bf16x8*)(G.Wk2 + wo);
                acc2[ct] = __builtin_amdgcn_mfma_f32_16x16x32_bf16(af[kc], b2, acc2[ct], 0, 0, 0);
            }
        }
#pragma unroll
        for (int ct = 0; ct < 8; ct++) {
            int col = ct * 16 + r16;
            float bb = G.bk[col];
#pragma unroll
            for (int j = 0; j < 4; j++) {
                int r = row0 + g * 4 + j;
                if (r < N) {
                    G.Zkw[(size_t)r * 128 + col] = f2bf(acc1[ct][j] + bb);
                    float v2 = acc2[ct][j];
                    int pk = __builtin_amdgcn_cvt_pk_fp8_f32(v2, v2, 0, false);
                    G.Ckw8[(size_t)r * 128 + col] = (unsigned char)(pk & 0xff);
                }
            }
        }
    } else {
        f32x4 acc1[8], acc2[8], acc3[8];
#pragma unroll
        for (int ct = 0; ct < 8; ct++) {
            f32x4 z = {0.f,0.f,0.f,0.f}; acc1[ct] = z; acc2[ct] = z; acc3[ct] = z;
        }
#pragma unroll
        for (int kc = 0; kc < 4; kc++) {
#pragma unroll
            for (int ct = 0; ct < 8; ct++) {
                int wo = ((ct * 16 + r16) << 7) + kc * 32 + g * 8;
                bf16x8 b1 = *(const bf16x8*)(G.Wr1 + wo);
                acc1[ct] = __builtin_amdgcn_mfma_f32_16x16x32_bf16(af[kc], b1, acc1[ct], 0, 0, 0);
                bf16x8 b2 = *(const bf16x8*)(G.Wr2 + wo);
                acc2[ct] = __builtin_amdgcn_mfma_f32_16x16x32_bf16(af[kc], b2, acc2[ct], 0, 0, 0);
                bf16x8 b3 = *(const bf16x8*)(G.Wr3 + wo);
                acc3[ct] = __builtin_amdgcn_mfma_f32_16x16x32_bf16(af[kc], b3, acc3[ct], 0, 0, 0);
            }
        }
#pragma unroll
        for (int ct = 0; ct < 8; ct++) {
            int col = ct * 16 + r16;
            float bb = G.br[col];
#pragma unroll
            for (int j = 0; j < 4; j++) {
                int r = row0 + g * 4 + j;
                if (r < N) {
                    G.Zrt[(size_t)r * 128 + col] = f2bf(acc1[ct][j] + bb);
                    G.Crt2[(size_t)r * 128 + col] = f2bf(acc2[ct][j]);
                    G.Crt3[(size_t)r * 128 + col] = f2bf(acc3[ct][j]);
                }
            }
        }
    }
}

__global__ __launch_bounds__(256) void gemm_sort_k(GemmJobs G, Rels R, int gemmBlocks) {
    if ((int)blockIdx.x < gemmBlocks) gemm_body<1>(G, blockIdx.x);
    else sortb_body(R, blockIdx.x - gemmBlocks);
}

__global__ __launch_bounds__(256) void gemm_l2_k(GemmJobs G) {
    gemm_body<0>(G, blockIdx.x);
}

// ---------------- bucket aggregation (R8 structure + scalar sp loads) ----------------
// Block = one 64-dst bucket, 8 waves, LDS accumulator. Wave w owns rows d=(r<<3)|w.
// Per 16-edge batch: the 16 byte-offsets are WAVE-UNIFORM -> read via uniform
// (SMEM) loads spw[j+2k(+1)], per-lane half-select by one cndmask. Halves (h)
// gather rows via uint2 (bf16) / uint (fp8): 8 VMEM per batch (was 16), and the
// offset fetch no longer chains on VMEM. shfl_xor(32) combine, non-atomic
// swizzled LDS flush (disjoint slots per half).
template <int FMT>   // 0: bf16 rows (256B), 1: fp8 rows (128B)
static __device__ __forceinline__ void row_accum(const unsigned* __restrict__ spw, int len,
                                                 const char* __restrict__ Y, int lb, int h,
                                                 f32x2& a01, f32x2& a23) {
    int j = 0;
#pragma unroll 1
    for (; j + 16 <= len; j += 16) {
        unsigned o[8];
#pragma unroll
        for (int k = 0; k < 8; k++) {
            unsigned oe = spw[j + 2 * k];       // uniform -> s_load
            unsigned oo = spw[j + 2 * k + 1];   // uniform -> s_load
            o[k] = h ? oo : oe;                 // per-lane half select
        }
        if (FMT == 0) {
            uint2 v[8];
#pragma unroll
            for (int k = 0; k < 8; k++) v[k] = *(const uint2*)(Y + o[k] + lb);
#pragma unroll
            for (int k = 0; k < 8; k++) {
                f32x2 x01 = { __uint_as_float(v[k].x << 16), __uint_as_float(v[k].x & 0xffff0000u) };
                f32x2 x23 = { __uint_as_float(v[k].y << 16), __uint_as_float(v[k].y & 0xffff0000u) };
                a01 += x01; a23 += x23;
            }
        } else {
            unsigned v[8];
#pragma unroll
            for (int k = 0; k < 8; k++) v[k] = *(const unsigned*)(Y + o[k] + lb);
#pragma unroll
            for (int k = 0; k < 8; k++) {
                auto lo = __builtin_amdgcn_cvt_pk_f32_fp8(v[k], false);
                auto hi = __builtin_amdgcn_cvt_pk_f32_fp8(v[k], true);
                a01[0] += lo[0]; a01[1] += lo[1];
                a23[0] += hi[0]; a23[1] += hi[1];
            }
        }
    }
    if (j < len) {   // tail <16 edges, predicated (divergent sp loads OK here)
#pragma unroll
        for (int k = 0; k < 8; k++) {
            int e = j + 2 * k + h;
            int ec = e < len ? e : len - 1;
            bool live = e < len;
            unsigned o = spw[ec];
            if (FMT == 0) {
                uint2 v = *(const uint2*)(Y + o + lb);
                unsigned vx = live ? v.x : 0u, vy = live ? v.y : 0u;
                f32x2 x01 = { __uint_as_float(vx << 16), __uint_as_float(vx & 0xffff0000u) };
                f32x2 x23 = { __uint_as_float(vy << 16), __uint_as_float(vy & 0xffff0000u) };
                a01 += x01; a23 += x23;
            } else {
                unsigned vv = *(const unsigned*)(Y + o + lb);
                vv = live ? vv : 0u;
                auto lo = __builtin_amdgcn_cvt_pk_f32_fp8(vv, false);
                auto hi = __builtin_amdgcn_cvt_pk_f32_fp8(vv, true);
                a01[0] += lo[0]; a01[1] += lo[1];
                a23[0] += hi[0]; a23[1] += hi[1];
            }
        }
    }
}

template <int FMT>
static __device__ __forceinline__ void agg_rel(float* acc, int b, int w, int h, int q,
                                               int dst0,
                                               const unsigned* __restrict__ sp,
                                               const int* __restrict__ goff,
                                               const float* __restrict__ invd,
                                               const char* __restrict__ Ybase) {
    int lb = FMT ? (q << 2) : (q << 3);
#pragma unroll 1
    for (int r = 0; r < 8; r++) {
        int gi = b * 64 + w * 8 + r;
        int jg0 = __builtin_amdgcn_readfirstlane(goff[gi]);
        int jg1 = __builtin_amdgcn_readfirstlane(goff[gi + 1]);
        if (jg0 >= jg1) continue;
        int d = (r << 3) | w;
        f32x2 a01 = {0.f, 0.f}, a23 = {0.f, 0.f};
        row_accum<FMT>(sp + jg0, jg1 - jg0, Ybase, lb, h, a01, a23);
        a01[0] += __shfl_xor(a01[0], 32);
        a01[1] += __shfl_xor(a01[1], 32);
        a23[0] += __shfl_xor(a23[0], 32);
        a23[1] += __shfl_xor(a23[1], 32);
        float inv = invd[dst0 + d];
        float v0 = (h ? a23[0] : a01[0]) * inv;
        float v1 = (h ? a23[1] : a01[1]) * inv;
        int ba = d * 128 + q + h * 64;
        acc[ba] += v0;
        acc[ba + 32] += v1;
    }
}

struct AggJob {
    const unsigned short* Zin; int Ndst;
    const unsigned* sp0; const int* goff0; const float* invd0; const void* Y0; int fmt0;
    const unsigned* sp1; const int* goff1; const float* invd1; const void* Y1; int fmt1;
    int nrel;
    float* OutF; unsigned short* OutB;
};

template <int RELU, int OUTBF16>
__global__ __launch_bounds__(512) void bagg2_k(AggJob JK, AggJob JR, int kwBlocks) {
    __shared__ float acc[BUCKET * 128];
    bool iskw = blockIdx.x < (unsigned)kwBlocks;
    AggJob J = iskw ? JK : JR;
    int b = iskw ? blockIdx.x : blockIdx.x - kwBlocks;
    int t = threadIdx.x;
    int dst0 = b << BSH;
    int nrow = J.Ndst - dst0; if (nrow > BUCKET) nrow = BUCKET;

    // init from Zin bf16 (swizzled: feature 4m+e at r*128 + e*32 + m)
    for (int c = t; c < BUCKET * 32; c += 512) {
        int r = c >> 5, m = c & 31;
        float z0 = 0.f, z1 = 0.f, z2 = 0.f, z3 = 0.f;
        if (r < nrow) {
            ushort4 z = *(const ushort4*)(J.Zin + (size_t)(dst0 + r) * 128 + (m << 2));
            z0 = bf2f(z.x); z1 = bf2f(z.y); z2 = bf2f(z.z); z3 = bf2f(z.w);
        }
        acc[r * 128 + m] = z0;
        acc[r * 128 + 32 + m] = z1;
        acc[r * 128 + 64 + m] = z2;
        acc[r * 128 + 96 + m] = z3;
    }
    __syncthreads();

    int w = t >> 6, lane = t & 63;
    int h = lane >> 5, q = lane & 31;
    if (J.fmt0 == 0) agg_rel<0>(acc, b, w, h, q, dst0, J.sp0, J.goff0, J.invd0, (const char*)J.Y0);
    else agg_rel<1>(acc, b, w, h, q, dst0, J.sp0, J.goff0, J.invd0, (const char*)J.Y0);
    if (J.nrel == 2) {
        if (J.fmt1 == 0) agg_rel<0>(acc, b, w, h, q, dst0, J.sp1, J.goff1, J.invd1, (const char*)J.Y1);
        else agg_rel<1>(acc, b, w, h, q, dst0, J.sp1, J.goff1, J.invd1, (const char*)J.Y1);
    }
    __syncthreads();
    for (int c = t; c < BUCKET * 32; c += 512) {
        int r = c >> 5, m = c & 31;
        if (r < nrow) {
            float x0 = acc[r * 128 + m];
            float x1 = acc[r * 128 + 32 + m];
            float x2 = acc[r * 128 + 64 + m];
            float x3 = acc[r * 128 + 96 + m];
            if (RELU) {
                x0 = fmaxf(x0, 0.f); x1 = fmaxf(x1, 0.f);
                x2 = fmaxf(x2, 0.f); x3 = fmaxf(x3, 0.f);
            }
            size_t o = (size_t)(dst0 + r) * 128 + (m << 2);
            if (OUTBF16) {
                ushort4 ov;
                ov.x = f2bf(x0); ov.y = f2bf(x1); ov.z = f2bf(x2); ov.w = f2bf(x3);
                *(ushort4*)(J.OutB + o) = ov;
            } else {
                *(float4*)(J.OutF + o) = make_float4(x0, x1, x2, x3);
            }
        }
    }
}

// ---------------- launch ----------------

static inline size_t align256(size_t x) { return (x + 255) & ~size_t(255); }

extern "C" void kernel_launch(void* const* d_in, const int* in_sizes, int n_in,
                              void* d_out, int out_size, void* d_ws, size_t ws_size,
                              hipStream_t stream) {
    const float* x_kw = (const float*)d_in[0];
    const float* x_rt = (const float*)d_in[1];
    const int* src_a = (const int*)d_in[2];
    const int* dst_a = (const int*)d_in[3];
    const int* src_b = (const int*)d_in[4];
    const int* dst_b = (const int*)d_in[5];
    const int* src_c = (const int*)d_in[6];
    const int* dst_c = (const int*)d_in[7];
    const float *Wl1a = (const float*)d_in[8],  *bl1a = (const float*)d_in[9],  *Wr1a = (const float*)d_in[10];
    const float *Wl1b = (const float*)d_in[11], *bl1b = (const float*)d_in[12], *Wr1b = (const float*)d_in[13];
    const float *Wl1c = (const float*)d_in[14], *bl1c = (const float*)d_in[15], *Wr1c = (const float*)d_in[16];
    const float *Wl2a = (const float*)d_in[17], *bl2a = (const float*)d_in[18], *Wr2a = (const float*)d_in[19];
    const float *Wl2b = (const float*)d_in[20], *bl2b = (const float*)d_in[21], *Wr2b = (const float*)d_in[22];
    const float *Wl2c = (const float*)d_in[23], *bl2c = (const float*)d_in[24], *Wr2c = (const float*)d_in[25];

    const int NKW = in_sizes[0] / 128;
    const int NRT = in_sizes[1] / 128;
    const int EA = in_sizes[2], EB = in_sizes[4], EC = in_sizes[6];
    const int nb_kw = (NKW + BUCKET - 1) / BUCKET;
    const int nb_rt = (NRT + BUCKET - 1) / BUCKET;

    char* ws = (char*)d_ws;
    size_t off = 0;
    auto alloc = [&](size_t bytes) -> char* {
        off = align256(off);
        char* p = ws + off;
        off += bytes;
        return p;
    };
    unsigned short* Wt = (unsigned short*)alloc(10 * 16384 * 2);
    float* bc1 = (float*)alloc(128 * 4);
    float* bc2 = (float*)alloc(128 * 4);
    int* bcnt3 = (int*)alloc(3 * NBMAX * 4);
    int* bcur3 = (int*)alloc(3 * NBMAX * 4);
    int* boff_a = (int*)alloc((NBMAX + 1) * 4);
    int* boff_b = (int*)alloc((NBMAX + 1) * 4);
    int* boff_c = (int*)alloc((NBMAX + 1) * 4);
    int* goff_a = (int*)alloc(((size_t)nb_kw * 64 + 1) * 4);
    int* goff_b = (int*)alloc(((size_t)nb_kw * 64 + 1) * 4);
    int* goff_c = (int*)alloc(((size_t)nb_rt * 64 + 1) * 4);
    float* invd_a = (float*)alloc((size_t)NKW * 4);
    float* invd_b = (float*)alloc((size_t)NKW * 4);
    float* invd_c = (float*)alloc((size_t)NRT * 4);
    unsigned* pairs_a = (unsigned*)alloc((size_t)EA * 4);
    unsigned* pairs_b = (unsigned*)alloc((size_t)EB * 4);
    unsigned* pairs_c = (unsigned*)alloc((size_t)EC * 4);
    unsigned* sp_a = (unsigned*)alloc((size_t)EA * 4);
    unsigned* sp_b = (unsigned*)alloc((size_t)EB * 4);
    unsigned* sp_c = (unsigned*)alloc((size_t)EC * 4);
    unsigned short* Ya = (unsigned short*)alloc((size_t)NRT * 128 * 2);
    unsigned char*  Yb = (unsigned char*)alloc((size_t)NKW * 128);      // fp8
    unsigned short* Yc = (unsigned short*)alloc((size_t)NRT * 128 * 2);
    unsigned short* Zkw = (unsigned short*)alloc((size_t)NKW * 128 * 2);
    unsigned short* Zrt = (unsigned short*)alloc((size_t)NRT * 128 * 2);
    unsigned short* kw1_bf = (unsigned short*)alloc((size_t)NKW * 128 * 2);
    unsigned short* rt1_bf = (unsigned short*)alloc((size_t)NRT * 128 * 2);
    (void)ws_size;

    float* out_kw = (float*)d_out;
    float* out_rt = out_kw + (size_t)NKW * 128;

    // ---- Rels ----
    Rels R;
    int hA = 128, hB = 128, hC = 64;
    int sA = (EA + 8191) / 8192, sB = (EB + 8191) / 8192, sC = (EC + 8191) / 8192;
    R.r[0] = {src_a, dst_a, EA, nb_kw, NKW, 0, hA, 0, sA, 0, 8,
              bcnt3, boff_a, bcur3, pairs_a, sp_a, goff_a, invd_a};
    R.r[1] = {src_b, dst_b, EB, nb_kw, NKW, hA, hB, sA, sB, nb_kw, 7,   // fp8 rows: 128 B
              bcnt3 + NBMAX, boff_b, bcur3 + NBMAX, pairs_b, sp_b, goff_b, invd_b};
    R.r[2] = {src_c, dst_c, EC, nb_rt, NRT, hA + hB, hC, sA + sB, sC, 2 * nb_kw, 8,
              bcnt3 + 2 * NBMAX, boff_c, bcur3 + 2 * NBMAX, pairs_c, sp_c, goff_c, invd_c};

    // ---- prep + hist ----
    hipMemsetAsync(bcnt3, 0, 3 * NBMAX * 4, stream);
    PrepArgs pa;
    pa.W[0] = Wr1a; pa.Wa[0] = Wr1b;
    pa.W[1] = Wl1a; pa.Wa[1] = nullptr;
    pa.W[2] = Wl1b; pa.Wa[2] = nullptr;
    pa.W[3] = Wl1c; pa.Wa[3] = nullptr;
    pa.W[4] = Wr1c; pa.Wa[4] = nullptr;
    pa.W[5] = Wr2a; pa.Wa[5] = Wr2b;
    pa.W[6] = Wl2a; pa.Wa[6] = nullptr;
    pa.W[7] = Wl2b; pa.Wa[7] = nullptr;
    pa.W[8] = Wl2c; pa.Wa[8] = nullptr;
    pa.W[9] = Wr2c; pa.Wa[9] = nullptr;
    pa.b1a = bl1a; pa.b1b = bl1b; pa.b2a = bl2a; pa.b2b = bl2b;
    prep_hist_k<<<641 + hA + hB + hC, 256, 0, stream>>>(pa, Wt, bc1, bc2, R, 641);
    unsigned short* W0 = Wt + 0 * 16384;
    unsigned short* W1 = Wt + 1 * 16384;
    unsigned short* W2 = Wt + 2 * 16384;
    unsigned short* W3 = Wt + 3 * 16384;
    unsigned short* W4 = Wt + 4 * 16384;
    unsigned short* W5 = Wt + 5 * 16384;
    unsigned short* W6 = Wt + 6 * 16384;
    unsigned short* W7 = Wt + 7 * 16384;
    unsigned short* W8 = Wt + 8 * 16384;
    unsigned short* W9 = Wt + 9 * 16384;

    bscan3_k<<<3, 1024, 0, stream>>>(R);
    bscatter3_k<<<sA + sB + sC, 256, 0, stream>>>(R);

    const int kwB = (NKW + 63) / 64, rtB = (NRT + 63) / 64;
    const int nsort = 2 * nb_kw + nb_rt;

    // ---- layer 1: gemms + bucket sort in one launch (independent) ----
    GemmJobs G1;
    G1.Akw = x_kw; G1.Nkw = NKW; G1.Wk1 = W0; G1.bk = bc1; G1.Zkw = Zkw; G1.Wk2 = W2; G1.Ckw8 = Yb;
    G1.Art = x_rt; G1.Nrt = NRT; G1.Wr1 = W4; G1.br = bl1c; G1.Zrt = Zrt;
    G1.Wr2 = W1; G1.Crt2 = Ya; G1.Wr3 = W3; G1.Crt3 = Yc;
    G1.kwBlocks = kwB;
    gemm_sort_k<<<kwB + rtB + nsort, 256, 0, stream>>>(G1, R, kwB + rtB);

    AggJob JK1 = {Zkw, NKW, sp_a, goff_a, invd_a, Ya, 0, sp_b, goff_b, invd_b, Yb, 1, 2,
                  nullptr, kw1_bf};
    AggJob JR1 = {Zrt, NRT, sp_c, goff_c, invd_c, Yc, 0, nullptr, nullptr, nullptr, nullptr, 0, 1,
                  nullptr, rt1_bf};
    bagg2_k<1, 1><<<nb_kw + nb_rt, 512, 0, stream>>>(JK1, JR1, nb_kw);

    // ---- layer 2 ----
    GemmJobs G2;
    G2.Akw = kw1_bf; G2.Nkw = NKW; G2.Wk1 = W5; G2.bk = bc2; G2.Zkw = Zkw; G2.Wk2 = W7; G2.Ckw8 = Yb;
    G2.Art = rt1_bf; G2.Nrt = NRT; G2.Wr1 = W9; G2.br = bl2c; G2.Zrt = Zrt;
    G2.Wr2 = W6; G2.Crt2 = Ya; G2.Wr3 = W8; G2.Crt3 = Yc;
    G2.kwBlocks = kwB;
    gemm_l2_k<<<kwB + rtB, 256, 0, stream>>>(G2);

    AggJob JK2 = {Zkw, NKW, sp_a, goff_a, invd_a, Ya, 0, sp_b, goff_b, invd_b, Yb, 1, 2,
                  out_kw, nullptr};
    AggJob JR2 = {Zrt, NRT, sp_c, goff_c, invd_c, Yc, 0, nullptr, nullptr, nullptr, nullptr, 0, 1,
                  out_rt, nullptr};
    bagg2_k<0, 0><<<nb_kw + nb_rt, 512, 0, stream>>>(JK2, JR2, nb_kw);
}